// Round 17
// baseline (1020.169 us; speedup 1.0000x reference)
//
#include <hip/hip_runtime.h>
#include <hip/hip_bf16.h>

typedef __attribute__((ext_vector_type(4))) float f32x4;
typedef __attribute__((ext_vector_type(8))) __bf16 bf16x8;
typedef __attribute__((ext_vector_type(8))) unsigned short u16x8;

#define SCALE_ 0.17677669529663687f  /* 32^-0.5 */
#define RS 19267584                   /* 50176*384: q/k/v region stride (elems) per chunk */
#define HT 50176                      /* tokens per chunk */

// ---------- workspace layout (bytes) ----------
#define OFF_R1 77070336ull
#define OFF_WB 154140672ull
#define OFF_WT 156205056ull           // f32 [9][384] dw weights
#define OFF_SB 156218880ull           // f32 S1[384] | bb[384]

__device__ __forceinline__ __bf16 tobf(float f) {
  __hip_bfloat16 h = __float2bfloat16(f);
  return __builtin_bit_cast(__bf16, h);
}
__device__ __forceinline__ unsigned short f2u(float f) {
  return __builtin_bit_cast(unsigned short, __float2bfloat16(f));
}

// ---------- fp32 -> bf16 weight copy ----------
__global__ __launch_bounds__(256) void cvt_kernel(const float* __restrict__ src,
                                                  __hip_bfloat16* __restrict__ dst, int n) {
  int i = blockIdx.x * 256 + threadIdx.x;
  int stride = gridDim.x * 256;
  for (; i < n; i += stride) dst[i] = __float2bfloat16(src[i]);
}

// ---------- repack dw weights [384][9] -> [9][384] ----------
__global__ __launch_bounds__(256) void dwrep_kernel(const float* __restrict__ src,
                                                    float* __restrict__ dst) {
  int i = blockIdx.x * 256 + threadIdx.x;
  if (i < 3456) {
    int c = i / 9, k = i - c * 9;
    dst[k * 384 + c] = src[i];
  }
}

// ---------- c1 prep: gc1 = bf16(c1_w * n2g); S1[n] = sum(gc1); bb[n] = c1_b + sum(n2b*c1_w) ----------
__global__ __launch_bounds__(256) void c1prep_kernel(const float* __restrict__ c1w,
                                                     const float* __restrict__ c1b,
                                                     const float* __restrict__ g,
                                                     const float* __restrict__ b,
                                                     __hip_bfloat16* __restrict__ gc1,
                                                     float* __restrict__ S1,
                                                     float* __restrict__ bb) {
  const int n = blockIdx.x * 4 + (threadIdx.x >> 6);
  const int lane = threadIdx.x & 63;
  float s1 = 0.f, sb = 0.f;
  for (int k = lane; k < 384; k += 64) {
    float w = c1w[n * 384 + k];
    __hip_bfloat16 gw = __float2bfloat16(w * g[k]);
    gc1[n * 384 + k] = gw;
    s1 += __bfloat162float(gw);
    sb += w * b[k];
  }
#pragma unroll
  for (int m = 1; m < 64; m <<= 1) { s1 += __shfl_xor(s1, m, 64); sb += __shfl_xor(sb, m, 64); }
  if (lane == 0) { S1[n] = s1; bb[n] = c1b[n] + sb; }
}

// ---------- qkvln: LN1 fused into QKV GEMM; A = LN1(x) gathered via window map ----------
__global__ __launch_bounds__(256) void qkvln_gemm(const float* __restrict__ xc,   // [50176][384] chunk
                                                  const float* __restrict__ lg,
                                                  const float* __restrict__ lb,
                                                  const __hip_bfloat16* __restrict__ W,  // [1152][384]
                                                  const float* __restrict__ bias,
                                                  __hip_bfloat16* __restrict__ outp) {
  const int tid = threadIdx.x;
  const int lane = tid & 63, wave = tid >> 6;
  const int g = lane >> 4, r = lane & 15;
  const int row0 = blockIdx.x * 64;
  const int col0 = blockIdx.y * 192;
  const int n0 = wave * 48;

  __shared__ __align__(16) __hip_bfloat16 Al[64][40];
  __shared__ __align__(16) __hip_bfloat16 Bl[192][40];

  const int s_row = tid >> 2, s_c = (tid & 3) * 8;

  // windowed row -> chunk-local image row (inverse roll + window partition)
  const float* xr;
  {
    int t = row0 + s_row;
    int bl = t / 3136, lw = t - bl * 3136;
    int widx = lw / 49, n = lw - widx * 49;
    int n7 = n / 7;
    int hp = (widx >> 3) * 7 + n7, wp = (widx & 7) * 7 + (n - n7 * 7);
    int ii = hp + 3; if (ii >= 56) ii -= 56;
    int jj = wp + 3; if (jj >= 56) jj -= 56;
    xr = xc + ((size_t)bl * 3136 + ii * 56 + jj) * 384;
  }

  // ---- stats pre-pass: 4 adjacent lanes per row ----
  float mean, rstd;
  {
    float s = 0.f, sq = 0.f;
#pragma unroll
    for (int c = 0; c < 12; ++c) {
      const float4* p = (const float4*)(xr + c * 32 + s_c);
      float4 a = p[0], b = p[1];
      s += a.x + a.y + a.z + a.w + b.x + b.y + b.z + b.w;
      sq += a.x * a.x + a.y * a.y + a.z * a.z + a.w * a.w +
            b.x * b.x + b.y * b.y + b.z * b.z + b.w * b.w;
    }
#pragma unroll
    for (int m = 1; m < 4; m <<= 1) { s += __shfl_xor(s, m, 64); sq += __shfl_xor(sq, m, 64); }
    mean = s * (1.f / 384.f);
    float var = sq * (1.f / 384.f) - mean * mean;
    rstd = rsqrtf(var + 1e-5f);
  }

  // normalized bf16x8 producer (x L2-hot after pre-pass)
  auto mk = [&](int kb) -> bf16x8 {
    const float4* p = (const float4*)(xr + kb);
    float4 xa = p[0], xb = p[1];
    const float4* gp = (const float4*)(lg + kb);
    float4 ga = gp[0], gb = gp[1];
    const float4* bp = (const float4*)(lb + kb);
    float4 ba = bp[0], bbv = bp[1];
    bf16x8 t;
    t[0] = tobf((xa.x - mean) * rstd * ga.x + ba.x);
    t[1] = tobf((xa.y - mean) * rstd * ga.y + ba.y);
    t[2] = tobf((xa.z - mean) * rstd * ga.z + ba.z);
    t[3] = tobf((xa.w - mean) * rstd * ga.w + ba.w);
    t[4] = tobf((xb.x - mean) * rstd * gb.x + bbv.x);
    t[5] = tobf((xb.y - mean) * rstd * gb.y + bbv.y);
    t[6] = tobf((xb.z - mean) * rstd * gb.z + bbv.z);
    t[7] = tobf((xb.w - mean) * rstd * gb.w + bbv.w);
    return t;
  };

  f32x4 acc[4][3] = {};
  bf16x8 a_reg = mk(s_c);
  bf16x8 b_reg[3];
#pragma unroll
  for (int h = 0; h < 3; ++h)
    b_reg[h] = *(const bf16x8*)(W + (size_t)(col0 + s_row + 64 * h) * 384 + s_c);

  for (int kk = 0; kk < 12; ++kk) {
    *(bf16x8*)(&Al[s_row][s_c]) = a_reg;
#pragma unroll
    for (int h = 0; h < 3; ++h) *(bf16x8*)(&Bl[s_row + 64 * h][s_c]) = b_reg[h];
    __syncthreads();
    if (kk + 1 < 12) {
      const int kb = (kk + 1) * 32 + s_c;
      a_reg = mk(kb);
#pragma unroll
      for (int h = 0; h < 3; ++h)
        b_reg[h] = *(const bf16x8*)(W + (size_t)(col0 + s_row + 64 * h) * 384 + kb);
    }
    bf16x8 af[4];
#pragma unroll
    for (int mt = 0; mt < 4; ++mt) af[mt] = *(const bf16x8*)(&Al[mt * 16 + r][g * 8]);
#pragma unroll
    for (int nt = 0; nt < 3; ++nt) {
      bf16x8 bf = *(const bf16x8*)(&Bl[n0 + nt * 16 + r][g * 8]);
#pragma unroll
      for (int mt = 0; mt < 4; ++mt)
        acc[mt][nt] = __builtin_amdgcn_mfma_f32_16x16x32_bf16(af[mt], bf, acc[mt][nt], 0, 0, 0);
    }
    __syncthreads();
  }

#pragma unroll
  for (int mt = 0; mt < 4; ++mt) {
#pragma unroll
    for (int j = 0; j < 4; ++j) {
      const int row = row0 + mt * 16 + g * 4 + j;
#pragma unroll
      for (int nt = 0; nt < 3; ++nt) {
        const int col = col0 + n0 + nt * 16 + r;
        float v = acc[mt][nt][j] + bias[col];
        const int s = col / 384, cs = col - s * 384;
        if (s == 0) v *= SCALE_;
        ((__hip_bfloat16*)outp)[(size_t)s * RS + (size_t)row * 384 + cs] = __float2bfloat16(v);
      }
    }
  }
}

// ---------- gemm5 (C2): 64x192 block, LDS-staged ----------
template <int KD>
__global__ __launch_bounds__(256) void gemm5_c2(const __hip_bfloat16* __restrict__ Ap,
                                                const __hip_bfloat16* __restrict__ W,
                                                const float* __restrict__ bias,
                                                const float* __restrict__ p0,
                                                const float* __restrict__ p1,
                                                const float* __restrict__ p2,
                                                float* __restrict__ outp) {
  constexpr int KS = KD / 32;
  const int tid = threadIdx.x;
  const int lane = tid & 63, wave = tid >> 6;
  const int g = lane >> 4, r = lane & 15;
  const int row0 = blockIdx.x * 64;
  const int col0 = blockIdx.y * 192;
  const int n0 = wave * 48;

  __shared__ __align__(16) __hip_bfloat16 Al[64][40];
  __shared__ __align__(16) __hip_bfloat16 Bl[192][40];

  const int s_row = tid >> 2, s_c = (tid & 3) * 8;
  const size_t arow = (size_t)(row0 + s_row);

  f32x4 acc[4][3] = {};
  bf16x8 a_reg = *(const bf16x8*)(Ap + arow * KD + s_c);
  bf16x8 b_reg[3];
#pragma unroll
  for (int h = 0; h < 3; ++h)
    b_reg[h] = *(const bf16x8*)(W + (size_t)(col0 + s_row + 64 * h) * KD + s_c);

  for (int kk = 0; kk < KS; ++kk) {
    *(bf16x8*)(&Al[s_row][s_c]) = a_reg;
#pragma unroll
    for (int h = 0; h < 3; ++h) *(bf16x8*)(&Bl[s_row + 64 * h][s_c]) = b_reg[h];
    __syncthreads();
    if (kk + 1 < KS) {
      const int kb = (kk + 1) * 32 + s_c;
      a_reg = *(const bf16x8*)(Ap + arow * KD + kb);
#pragma unroll
      for (int h = 0; h < 3; ++h)
        b_reg[h] = *(const bf16x8*)(W + (size_t)(col0 + s_row + 64 * h) * KD + kb);
    }
    bf16x8 af[4];
#pragma unroll
    for (int mt = 0; mt < 4; ++mt) af[mt] = *(const bf16x8*)(&Al[mt * 16 + r][g * 8]);
#pragma unroll
    for (int nt = 0; nt < 3; ++nt) {
      bf16x8 bf = *(const bf16x8*)(&Bl[n0 + nt * 16 + r][g * 8]);
#pragma unroll
      for (int mt = 0; mt < 4; ++mt)
        acc[mt][nt] = __builtin_amdgcn_mfma_f32_16x16x32_bf16(af[mt], bf, acc[mt][nt], 0, 0, 0);
    }
    __syncthreads();
  }

#pragma unroll
  for (int mt = 0; mt < 4; ++mt) {
#pragma unroll
    for (int j = 0; j < 4; ++j) {
      const int row = row0 + mt * 16 + g * 4 + j;
#pragma unroll
      for (int nt = 0; nt < 3; ++nt) {
        const int col = col0 + n0 + nt * 16 + r;
        float v = acc[mt][nt][j] + bias[col];
        float y = v * p0[col] + p1[col];
        outp[(size_t)row * 384 + col] = p2[(size_t)row * 384 + col] + y;
      }
    }
  }
}

// ---------- se2: x2 = x1b*sigmoid(g1@W^T+b), + per-row partial LN stats (deterministic) ----------
__global__ __launch_bounds__(256) void se2_kernel(const __hip_bfloat16* __restrict__ g1,
                                                  const __hip_bfloat16* __restrict__ W,
                                                  const float* __restrict__ bias,
                                                  const __hip_bfloat16* __restrict__ x1b,
                                                  float* __restrict__ x2out,
                                                  float* __restrict__ stats) {
  constexpr int KD = 192;
  const int tid = threadIdx.x;
  const int lane = tid & 63, wave = tid >> 6;
  const int g = lane >> 4, r = lane & 15;
  const int row0 = blockIdx.x * 64;
  const int col0 = blockIdx.y * 192;
  const int n0 = wave * 48;

  __shared__ __align__(16) __hip_bfloat16 Al[64][40];
  __shared__ __align__(16) __hip_bfloat16 Bl[192][40];
  __shared__ float st[512];

  const int s_row = tid >> 2, s_c = (tid & 3) * 8;
  const size_t arow = (size_t)(row0 + s_row);

  f32x4 acc[4][3] = {};
  bf16x8 a_reg = *(const bf16x8*)(g1 + arow * KD + s_c);
  bf16x8 b_reg[3];
#pragma unroll
  for (int h = 0; h < 3; ++h)
    b_reg[h] = *(const bf16x8*)(W + (size_t)(col0 + s_row + 64 * h) * KD + s_c);

  for (int kk = 0; kk < 6; ++kk) {
    *(bf16x8*)(&Al[s_row][s_c]) = a_reg;
#pragma unroll
    for (int h = 0; h < 3; ++h) *(bf16x8*)(&Bl[s_row + 64 * h][s_c]) = b_reg[h];
    __syncthreads();
    if (kk + 1 < 6) {
      const int kb = (kk + 1) * 32 + s_c;
      a_reg = *(const bf16x8*)(g1 + arow * KD + kb);
#pragma unroll
      for (int h = 0; h < 3; ++h)
        b_reg[h] = *(const bf16x8*)(W + (size_t)(col0 + s_row + 64 * h) * KD + kb);
    }
    bf16x8 af[4];
#pragma unroll
    for (int mt = 0; mt < 4; ++mt) af[mt] = *(const bf16x8*)(&Al[mt * 16 + r][g * 8]);
#pragma unroll
    for (int nt = 0; nt < 3; ++nt) {
      bf16x8 bf = *(const bf16x8*)(&Bl[n0 + nt * 16 + r][g * 8]);
#pragma unroll
      for (int mt = 0; mt < 4; ++mt)
        acc[mt][nt] = __builtin_amdgcn_mfma_f32_16x16x32_bf16(af[mt], bf, acc[mt][nt], 0, 0, 0);
    }
    __syncthreads();
  }

#pragma unroll
  for (int mt = 0; mt < 4; ++mt) {
#pragma unroll
    for (int j = 0; j < 4; ++j) {
      const int lrow = mt * 16 + g * 4 + j;
      const size_t ob = (size_t)(row0 + lrow) * 384;
      float s = 0.f, sq = 0.f;
#pragma unroll
      for (int nt = 0; nt < 3; ++nt) {
        const int col = col0 + n0 + nt * 16 + r;
        float v = acc[mt][nt][j] + bias[col];
        float gate = 1.f / (1.f + __expf(-v));
        float x1v = __bfloat162float(x1b[ob + col]);
        float x2 = x1v * gate;
        x2out[ob + col] = x2;
        s += x2; sq += x2 * x2;
      }
#pragma unroll
      for (int m = 1; m < 16; m <<= 1) { s += __shfl_xor(s, m, 64); sq += __shfl_xor(sq, m, 64); }
      if (r == 0) { st[wave * 128 + lrow] = s; st[wave * 128 + 64 + lrow] = sq; }
    }
  }
  __syncthreads();
  if (tid < 64) {
    float s = st[tid] + st[128 + tid] + st[256 + tid] + st[384 + tid];
    float sq = st[64 + tid] + st[192 + tid] + st[320 + tid] + st[448 + tid];
    stats[(size_t)(row0 + tid) * 4 + blockIdx.y * 2] = s;
    stats[(size_t)(row0 + tid) * 4 + blockIdx.y * 2 + 1] = sq;
  }
}

// ---------- c1ln: y1 = gelu(LN2(x2) @ c1^T)*bn1+bn1b with LN folded (gc1/S1/bb) ----------
__global__ __launch_bounds__(256) void c1ln_kernel(const float* __restrict__ x2,
                                                   const float* __restrict__ stats,
                                                   const __hip_bfloat16* __restrict__ gc1,
                                                   const float* __restrict__ S1,
                                                   const float* __restrict__ bb,
                                                   const float* __restrict__ bn1g_,
                                                   const float* __restrict__ bn1b_,
                                                   __hip_bfloat16* __restrict__ y1) {
  const int tid = threadIdx.x;
  const int lane = tid & 63, wave = tid >> 6;
  const int g = lane >> 4, r = lane & 15;
  const int row0 = blockIdx.x * 64;
  const int col0 = blockIdx.y * 192;
  const int n0 = wave * 48;

  __shared__ __align__(16) __hip_bfloat16 Al[64][40];
  __shared__ __align__(16) __hip_bfloat16 Bl[192][40];
  __shared__ float mean_l[64], rstd_l[64];

  const int s_row = tid >> 2, s_c = (tid & 3) * 8;
  const size_t abase = (size_t)(row0 + s_row) * 384;

  if (tid < 64) {
    const size_t row = row0 + tid;
    float s = stats[row * 4] + stats[row * 4 + 2];
    float sq = stats[row * 4 + 1] + stats[row * 4 + 3];
    float mean = s * (1.f / 384.f);
    float var = sq * (1.f / 384.f) - mean * mean;
    mean_l[tid] = mean;
    rstd_l[tid] = rsqrtf(var + 1e-5f);
  }

  f32x4 acc[4][3] = {};
  bf16x8 a_reg;
  {
    const float4* sp = (const float4*)(x2 + abase + s_c);
    float4 a = sp[0], b = sp[1];
    a_reg[0] = tobf(a.x); a_reg[1] = tobf(a.y); a_reg[2] = tobf(a.z); a_reg[3] = tobf(a.w);
    a_reg[4] = tobf(b.x); a_reg[5] = tobf(b.y); a_reg[6] = tobf(b.z); a_reg[7] = tobf(b.w);
  }
  bf16x8 b_reg[3];
#pragma unroll
  for (int h = 0; h < 3; ++h)
    b_reg[h] = *(const bf16x8*)(gc1 + (size_t)(col0 + s_row + 64 * h) * 384 + s_c);

  for (int kk = 0; kk < 12; ++kk) {
    *(bf16x8*)(&Al[s_row][s_c]) = a_reg;
#pragma unroll
    for (int h = 0; h < 3; ++h) *(bf16x8*)(&Bl[s_row + 64 * h][s_c]) = b_reg[h];
    __syncthreads();
    if (kk + 1 < 12) {
      const int kb = (kk + 1) * 32 + s_c;
      const float4* sp = (const float4*)(x2 + abase + kb);
      float4 a = sp[0], b = sp[1];
      a_reg[0] = tobf(a.x); a_reg[1] = tobf(a.y); a_reg[2] = tobf(a.z); a_reg[3] = tobf(a.w);
      a_reg[4] = tobf(b.x); a_reg[5] = tobf(b.y); a_reg[6] = tobf(b.z); a_reg[7] = tobf(b.w);
#pragma unroll
      for (int h = 0; h < 3; ++h)
        b_reg[h] = *(const bf16x8*)(gc1 + (size_t)(col0 + s_row + 64 * h) * 384 + kb);
    }
    bf16x8 af[4];
#pragma unroll
    for (int mt = 0; mt < 4; ++mt) af[mt] = *(const bf16x8*)(&Al[mt * 16 + r][g * 8]);
#pragma unroll
    for (int nt = 0; nt < 3; ++nt) {
      bf16x8 bf = *(const bf16x8*)(&Bl[n0 + nt * 16 + r][g * 8]);
#pragma unroll
      for (int mt = 0; mt < 4; ++mt)
        acc[mt][nt] = __builtin_amdgcn_mfma_f32_16x16x32_bf16(af[mt], bf, acc[mt][nt], 0, 0, 0);
    }
    __syncthreads();
  }

#pragma unroll
  for (int mt = 0; mt < 4; ++mt) {
#pragma unroll
    for (int j = 0; j < 4; ++j) {
      const int rl = mt * 16 + g * 4 + j;
      const int row = row0 + rl;
      const float mean = mean_l[rl], rstd = rstd_l[rl];
#pragma unroll
      for (int nt = 0; nt < 3; ++nt) {
        const int col = col0 + n0 + nt * 16 + r;
        float v = rstd * (acc[mt][nt][j] - mean * S1[col]) + bb[col];
        float gl = 0.5f * v * (1.f + erff(v * 0.70710678118654752f));
        y1[(size_t)row * 384 + col] = __float2bfloat16(gl * bn1g_[col] + bn1b_[col]);
      }
    }
  }
}

// ---------- proj: x1 = x + proj(ao); x1 -> bf16 only; fused SE1 -> g1 ----------
__global__ __launch_bounds__(256) void proj_kernel(const __hip_bfloat16* __restrict__ aoc0,
                                                   const __hip_bfloat16* __restrict__ aoc1,
                                                   const __hip_bfloat16* __restrict__ W,
                                                   const float* __restrict__ bias,
                                                   const float* __restrict__ x,
                                                   __hip_bfloat16* __restrict__ x1b,
                                                   const __hip_bfloat16* __restrict__ W2,
                                                   const float* __restrict__ bias2,
                                                   __hip_bfloat16* __restrict__ g1) {
  constexpr int NT = 6;
  const int tid = threadIdx.x;
  const int lane = tid & 63, wave = tid >> 6;
  const int g = lane >> 4, r = lane & 15;
  const int row0 = blockIdx.x * 64;
  const int n0 = wave * 96;

  __shared__ __align__(16) char smem[50176];
  auto Al = (__hip_bfloat16(*)[40])smem;
  auto Bl = (__hip_bfloat16(*)[40])(smem + 64 * 80);

  const int s_row = tid >> 2;
  const int s_c = (tid & 3) * 8;

  const __hip_bfloat16* ap;
  {
    int t = row0 + s_row;
    int b = t / 3136, l = t - b * 3136;
    int i = l / 56, j = l - i * 56;
    int hp = i >= 3 ? i - 3 : i + 53;
    int wp = j >= 3 ? j - 3 : j + 53;
    size_t arow = ((size_t)(b * 64 + (hp / 7) * 8 + wp / 7)) * 49 + (hp % 7) * 7 + (wp % 7);
    ap = (arow < (size_t)HT) ? (aoc0 + arow * 384) : (aoc1 + (arow - HT) * 384);
  }

  f32x4 acc[4][NT] = {};

  bf16x8 a_reg = *(const bf16x8*)(ap + s_c);
  bf16x8 b_reg[NT];
#pragma unroll
  for (int h = 0; h < NT; ++h)
    b_reg[h] = *(const bf16x8*)(W + (size_t)(s_row + 64 * h) * 384 + s_c);

  for (int kk = 0; kk < 12; ++kk) {
    *(bf16x8*)(&Al[s_row][s_c]) = a_reg;
#pragma unroll
    for (int h = 0; h < NT; ++h) *(bf16x8*)(&Bl[s_row + 64 * h][s_c]) = b_reg[h];
    __syncthreads();
    if (kk + 1 < 12) {
      const int kb = (kk + 1) * 32 + s_c;
      a_reg = *(const bf16x8*)(ap + kb);
#pragma unroll
      for (int h = 0; h < NT; ++h)
        b_reg[h] = *(const bf16x8*)(W + (size_t)(s_row + 64 * h) * 384 + kb);
    }
    bf16x8 af[4];
#pragma unroll
    for (int mt = 0; mt < 4; ++mt) af[mt] = *(const bf16x8*)(&Al[mt * 16 + r][g * 8]);
#pragma unroll
    for (int nt = 0; nt < NT; ++nt) {
      bf16x8 bf = *(const bf16x8*)(&Bl[n0 + nt * 16 + r][g * 8]);
#pragma unroll
      for (int mt = 0; mt < 4; ++mt)
        acc[mt][nt] = __builtin_amdgcn_mfma_f32_16x16x32_bf16(af[mt], bf, acc[mt][nt], 0, 0, 0);
    }
    __syncthreads();
  }

  auto Xt = (__hip_bfloat16(*)[392])smem;
#pragma unroll
  for (int mt = 0; mt < 4; ++mt)
#pragma unroll
    for (int j = 0; j < 4; ++j) {
      const int lrow = mt * 16 + g * 4 + j;
      const size_t ob = (size_t)(row0 + lrow) * 384;
#pragma unroll
      for (int nt = 0; nt < NT; ++nt) {
        const int col = n0 + nt * 16 + r;
        float v = acc[mt][nt][j] + bias[col] + x[ob + col];
        __hip_bfloat16 hb = __float2bfloat16(v);
        x1b[ob + col] = hb;
        Xt[lrow][col] = hb;
      }
    }
  __syncthreads();
  f32x4 acc2[4][3] = {};
  const int c0 = wave * 48;
  for (int kk = 0; kk < 12; ++kk) {
    bf16x8 af2[4];
#pragma unroll
    for (int mt = 0; mt < 4; ++mt)
      af2[mt] = *(const bf16x8*)(&Xt[mt * 16 + r][kk * 32 + g * 8]);
#pragma unroll
    for (int nt2 = 0; nt2 < 3; ++nt2) {
      bf16x8 b2 = *(const bf16x8*)(W2 + (size_t)(c0 + nt2 * 16 + r) * 384 + kk * 32 + g * 8);
#pragma unroll
      for (int mt = 0; mt < 4; ++mt)
        acc2[mt][nt2] = __builtin_amdgcn_mfma_f32_16x16x32_bf16(af2[mt], b2, acc2[mt][nt2], 0, 0, 0);
    }
  }
#pragma unroll
  for (int mt = 0; mt < 4; ++mt)
#pragma unroll
    for (int j = 0; j < 4; ++j) {
      const size_t row = row0 + mt * 16 + g * 4 + j;
#pragma unroll
      for (int nt2 = 0; nt2 < 3; ++nt2) {
        const int col2 = c0 + nt2 * 16 + r;
        float v = acc2[mt][nt2][j] + bias2[col2];
        g1[row * 192 + col2] = __float2bfloat16(fmaxf(v, 0.f));
      }
    }
}

// ---------- attention core: one 64-thread block per (window, head); ao chunk-local ----------
__global__ __launch_bounds__(64) void attn_core(const __hip_bfloat16* __restrict__ qkv,
                                                const float* __restrict__ rpb,
                                                __hip_bfloat16* __restrict__ ao, int win0) {
  const int bid = blockIdx.x;
  const int win_l = bid / 12, head = bid - win_l * 12;
  const int widx = (win0 + win_l) & 63;
  const int lane = threadIdx.x;
  const int g = lane >> 4, r = lane & 15;
  const int wbh = (widx >> 3) * 7, wbw = (widx & 7) * 7;
  const size_t rowbase = (size_t)(win_l * 49) * 384 + head * 32;
  const __hip_bfloat16* q_g = qkv + rowbase;
  const __hip_bfloat16* k_g = qkv + RS + rowbase;
  const __hip_bfloat16* v_g = qkv + 2 * RS + rowbase;

  __shared__ __align__(16) __hip_bfloat16 P_l[49 * 64];
  __shared__ __align__(16) unsigned short vT[32 * 72];

  bf16x8 zf;
#pragma unroll
  for (int i = 0; i < 8; ++i) zf[i] = tobf(0.f);

  for (int i = lane; i < 512; i += 64) {
    int d = i >> 4, t = 48 + (i & 15);
    vT[d * 72 + t] = 0;
  }
  if (lane < 49) {
#pragma unroll
    for (int c = 0; c < 4; ++c) {
      u16x8 vv = *(const u16x8*)(v_g + (size_t)lane * 384 + c * 8);
#pragma unroll
      for (int e = 0; e < 8; ++e) vT[(c * 8 + e) * 72 + lane] = vv[e];
    }
  }

  int yj4[4], xj4[4], rj4[4];
  bool val4[4];
#pragma unroll
  for (int nt = 0; nt < 4; ++nt) {
    int jt = nt * 16 + r;
    val4[nt] = jt < 49;
    int jc = val4[nt] ? jt : 0;
    int yj = jc / 7, xj = jc - yj * 7;
    yj4[nt] = yj; xj4[nt] = xj;
    int hj = wbh + yj, wj = wbw + xj;
    rj4[nt] = (hj < 49 ? 0 : (hj < 53 ? 1 : 2)) * 3 + (wj < 49 ? 0 : (wj < 53 ? 1 : 2));
  }

  f32x4 sA[4][4] = {};
  {
    bf16x8 qa[4];
#pragma unroll
    for (int mt = 0; mt < 4; ++mt) {
      int row = mt * 16 + r;
      qa[mt] = (row < 49) ? *(const bf16x8*)(q_g + (size_t)row * 384 + g * 8) : zf;
    }
#pragma unroll
    for (int nt = 0; nt < 4; ++nt) {
      int rowk = nt * 16 + r;
      bf16x8 kf = (rowk < 49) ? *(const bf16x8*)(k_g + (size_t)rowk * 384 + g * 8) : zf;
#pragma unroll
      for (int mt = 0; mt < 4; ++mt)
        sA[mt][nt] = __builtin_amdgcn_mfma_f32_16x16x32_bf16(qa[mt], kf, sA[mt][nt], 0, 0, 0);
    }
  }
#pragma unroll
  for (int mt = 0; mt < 4; ++mt) {
#pragma unroll
    for (int j = 0; j < 4; ++j) {
      const int it = mt * 16 + g * 4 + j;
      if (it < 49) {
        int yi = it / 7, xi = it - yi * 7;
        int hi = wbh + yi, wi2 = wbw + xi;
        int ri = (hi < 49 ? 0 : (hi < 53 ? 1 : 2)) * 3 + (wi2 < 49 ? 0 : (wi2 < 53 ? 1 : 2));
        float v4[4];
#pragma unroll
        for (int nt = 0; nt < 4; ++nt) {
          float sv = -1e30f;
          if (val4[nt]) {
            sv = sA[mt][nt][j] + rpb[((yi - yj4[nt] + 6) * 13 + (xi - xj4[nt] + 6)) * 12 + head];
            if (ri != rj4[nt]) sv -= 100.f;
          }
          v4[nt] = sv;
        }
        float mx = fmaxf(fmaxf(v4[0], v4[1]), fmaxf(v4[2], v4[3]));
#pragma unroll
        for (int m = 1; m < 16; m <<= 1) mx = fmaxf(mx, __shfl_xor(mx, m, 64));
        float sum = 0.f;
#pragma unroll
        for (int nt = 0; nt < 4; ++nt) { v4[nt] = __expf(v4[nt] - mx); sum += v4[nt]; }
#pragma unroll
        for (int m = 1; m < 16; m <<= 1) sum += __shfl_xor(sum, m, 64);
        float inv = 1.f / sum;
#pragma unroll
        for (int nt = 0; nt < 4; ++nt) {
          int col = nt * 16 + r;
          int swz = ((col >> 3) ^ (it & 7));
          P_l[it * 64 + swz * 8 + (col & 7)] = __float2bfloat16(v4[nt] * inv);
        }
      }
    }
  }
  f32x4 oA[4][2] = {};
#pragma unroll
  for (int ks = 0; ks < 2; ++ks) {
    bf16x8 pa[4];
#pragma unroll
    for (int mt = 0; mt < 4; ++mt) {
      int row = mt * 16 + r;
      int swz = (ks * 4 + g) ^ (row & 7);
      pa[mt] = (row < 49) ? *(const bf16x8*)(&P_l[row * 64 + swz * 8]) : zf;
    }
#pragma unroll
    for (int nt = 0; nt < 2; ++nt) {
      bf16x8 vbv = *(const bf16x8*)(&vT[(nt * 16 + r) * 72 + ks * 32 + g * 8]);
#pragma unroll
      for (int mt = 0; mt < 4; ++mt)
        oA[mt][nt] = __builtin_amdgcn_mfma_f32_16x16x32_bf16(pa[mt], vbv, oA[mt][nt], 0, 0, 0);
    }
  }
#pragma unroll
  for (int mt = 0; mt < 4; ++mt)
#pragma unroll
    for (int nt = 0; nt < 2; ++nt)
#pragma unroll
      for (int j = 0; j < 4; ++j) {
        int row = mt * 16 + g * 4 + j;
        if (row < 49)
          ao[((size_t)win_l * 49 + row) * 384 + head * 32 + nt * 16 + r] =
              __float2bfloat16(oA[mt][nt][j]);
      }
}

// ---------- depthwise 3x3 (NHWC) + gelu*bn2 ----------
__global__ __launch_bounds__(256) void dw_kernel(const __hip_bfloat16* __restrict__ y1,
                                                 const float* __restrict__ wt,
                                                 const float* __restrict__ wb,
                                                 const float* __restrict__ g2,
                                                 const float* __restrict__ b2,
                                                 __hip_bfloat16* __restrict__ y2) {
  const int tid = blockIdx.x * 256 + threadIdx.x;
  const int c8 = tid % 48;
  int t = tid / 48;
  const int q = t & 3; t >>= 2;
  const int hq = t % 56;
  const int b = t / 56;
  const int cb = c8 * 8;
  const int x0 = q * 14;

  float wr[9][8];
#pragma unroll
  for (int k = 0; k < 9; ++k) {
    float4 a = *(const float4*)(wt + k * 384 + cb);
    float4 c = *(const float4*)(wt + k * 384 + cb + 4);
    wr[k][0] = a.x; wr[k][1] = a.y; wr[k][2] = a.z; wr[k][3] = a.w;
    wr[k][4] = c.x; wr[k][5] = c.y; wr[k][6] = c.z; wr[k][7] = c.w;
  }
  if (hq == 0) {
#pragma unroll
    for (int k = 0; k < 3; ++k)
#pragma unroll
      for (int i = 0; i < 8; ++i) wr[k][i] = 0.f;
  }
  if (hq == 55) {
#pragma unroll
    for (int k = 6; k < 9; ++k)
#pragma unroll
      for (int i = 0; i < 8; ++i) wr[k][i] = 0.f;
  }
  float bias[8], gv[8], bv[8];
  {
    float4 a = *(const float4*)(wb + cb), c = *(const float4*)(wb + cb + 4);
    bias[0] = a.x; bias[1] = a.y; bias[2] = a.z; bias[3] = a.w;
    bias[4] = c.x; bias[5] = c.y; bias[6] = c.z; bias[7] = c.w;
    float4 d = *(const float4*)(g2 + cb), e = *(const float4*)(g2 + cb + 4);
    gv[0] = d.x; gv[1] = d.y; gv[2] = d.z; gv[3] = d.w;
    gv[4] = e.x; gv[5] = e.y; gv[6] = e.z; gv[7] = e.w;
    float4 f = *(const float4*)(b2 + cb), h = *(const float4*)(b2 + cb + 4);
    bv[0] = f.x; bv[1] = f.y; bv[2] = f.z; bv[3] = f.w;
    bv[4] = h.x; bv[5] = h.y; bv[6] = h.z; bv[7] = h.w;
  }
  const int hm = hq > 0 ? hq - 1 : 0;
  const int hp = hq < 55 ? hq + 1 : 55;
  const __hip_bfloat16* r0 = y1 + ((size_t)(b * 3136 + hm * 56)) * 384 + cb;
  const __hip_bfloat16* r1 = y1 + ((size_t)(b * 3136 + hq * 56)) * 384 + cb;
  const __hip_bfloat16* r2 = y1 + ((size_t)(b * 3136 + hp * 56)) * 384 + cb;
  __hip_bfloat16* op = y2 + ((size_t)(b * 3136 + hq * 56)) * 384 + cb;

  u16x8 zv;
#pragma unroll
  for (int i = 0; i < 8; ++i) zv[i] = 0;
#define LDC(rp, x) (((unsigned)(x) < 56u) ? *(const u16x8*)((rp) + (size_t)(x) * 384) : zv)

  u16x8 L0 = LDC(r0, x0 - 1), L1 = LDC(r1, x0 - 1), L2 = LDC(r2, x0 - 1);
  u16x8 C0 = LDC(r0, x0), C1 = LDC(r1, x0), C2 = LDC(r2, x0);
#pragma unroll
  for (int xi = 0; xi < 14; ++xi) {
    const int x = x0 + xi;
    u16x8 R0 = LDC(r0, x + 1), R1 = LDC(r1, x + 1), R2 = LDC(r2, x + 1);
    float acc[8];
#pragma unroll
    for (int i = 0; i < 8; ++i) acc[i] = bias[i];
#pragma unroll
    for (int i = 0; i < 8; ++i) {
      acc[i] += __uint_as_float((unsigned)L0[i] << 16) * wr[0][i];
      acc[i] += __uint_as_float((unsigned)C0[i] << 16) * wr[1][i];
      acc[i] += __uint_as_float((unsigned)R0[i] << 16) * wr[2][i];
      acc[i] += __uint_as_float((unsigned)L1[i] << 16) * wr[3][i];
      acc[i] += __uint_as_float((unsigned)C1[i] << 16) * wr[4][i];
      acc[i] += __uint_as_float((unsigned)R1[i] << 16) * wr[5][i];
      acc[i] += __uint_as_float((unsigned)L2[i] << 16) * wr[6][i];
      acc[i] += __uint_as_float((unsigned)C2[i] << 16) * wr[7][i];
      acc[i] += __uint_as_float((unsigned)R2[i] << 16) * wr[8][i];
    }
    u16x8 o;
#pragma unroll
    for (int i = 0; i < 8; ++i) {
      float u = acc[i];
      float gl = 0.5f * u * (1.f + erff(u * 0.70710678118654752f));
      o[i] = f2u(gl * gv[i] + bv[i]);
    }
    *(u16x8*)(op + (size_t)x * 384) = o;
    L0 = C0; L1 = C1; L2 = C2;
    C0 = R0; C1 = R1; C2 = R2;
  }
#undef LDC
}

extern "C" void kernel_launch(void* const* d_in, const int* in_sizes, int n_in, void* d_out,
                              int out_size, void* d_ws, size_t ws_size, hipStream_t stream) {
  (void)in_sizes; (void)n_in; (void)out_size; (void)ws_size;
  const float* x = (const float*)d_in[0];
  const float* n1g = (const float*)d_in[1];
  const float* n1b = (const float*)d_in[2];
  const float* qkv_w = (const float*)d_in[3];
  const float* qkv_b = (const float*)d_in[4];
  const float* rpb = (const float*)d_in[5];
  const float* proj_w = (const float*)d_in[6];
  const float* proj_b = (const float*)d_in[7];
  const float* se1_w = (const float*)d_in[8];
  const float* se1_b = (const float*)d_in[9];
  const float* se2_w = (const float*)d_in[10];
  const float* se2_b = (const float*)d_in[11];
  const float* n2g = (const float*)d_in[12];
  const float* n2b = (const float*)d_in[13];
  const float* c1_w = (const float*)d_in[14];
  const float* c1_b = (const float*)d_in[15];
  const float* bn1g = (const float*)d_in[16];
  const float* bn1b = (const float*)d_in[17];
  const float* dw_w = (const float*)d_in[18];
  const float* dw_b = (const float*)d_in[19];
  const float* bn2g = (const float*)d_in[20];
  const float* bn2b = (const float*)d_in[21];
  const float* c2_w = (const float*)d_in[22];
  const float* c2_b = (const float*)d_in[23];
  const float* bn3g = (const float*)d_in[24];
  const float* bn3b = (const float*)d_in[25];

  char* ws = (char*)d_ws;
  __hip_bfloat16* r0b = (__hip_bfloat16*)ws;              // R0: aoc1/stats/g1 -> y2
  __hip_bfloat16* r1b = (__hip_bfloat16*)(ws + OFF_R1);   // R1: x1b -> y1
  __hip_bfloat16* wbp = (__hip_bfloat16*)(ws + OFF_WB);
  float* wt = (float*)(ws + OFF_WT);
  float* S1 = (float*)(ws + OFF_SB);
  float* bb = S1 + 384;
  __hip_bfloat16* qkv_wb = wbp;             // 442368
  __hip_bfloat16* proj_wb = wbp + 442368;   // 147456
  __hip_bfloat16* se1_wb = wbp + 589824;    // 73728
  __hip_bfloat16* se2_wb = wbp + 663552;    // 73728
  __hip_bfloat16* gc1 = wbp + 737280;       // 147456 (c1_w * n2g, bf16)
  __hip_bfloat16* c2_wb = wbp + 884736;     // 147456
  float* out = (float*)d_out;

  // chunked ao locations
  __hip_bfloat16* aoc0 = (__hip_bfloat16*)d_out + 3 * RS;  // d_out tail (after qkv scratch)
  __hip_bfloat16* aoc1 = r0b;                              // R0[0:38.5MB]
  __hip_bfloat16* g1 = r0b + (size_t)HT * 384;             // R0[38.5:77MB]
  float* stats = (float*)r0b;                              // R0[0:1.6MB] (after proj done)

  cvt_kernel<<<1728, 256, 0, stream>>>(qkv_w, qkv_wb, 442368);
  cvt_kernel<<<576, 256, 0, stream>>>(proj_w, proj_wb, 147456);
  cvt_kernel<<<288, 256, 0, stream>>>(se1_w, se1_wb, 73728);
  cvt_kernel<<<288, 256, 0, stream>>>(se2_w, se2_wb, 73728);
  cvt_kernel<<<576, 256, 0, stream>>>(c2_w, c2_wb, 147456);
  c1prep_kernel<<<96, 256, 0, stream>>>(c1_w, c1_b, n2g, n2b, gc1, S1, bb);
  dwrep_kernel<<<14, 256, 0, stream>>>(dw_w, wt);

  // attention: 2 chunks; LN1 fused into qkv; qkv -> d_out[0:115.6MB];
  // ao: chunk0 -> d_out tail, chunk1 -> R0[0:38.5]
  for (int c = 0; c < 2; ++c) {
    const float* xc = x + (size_t)c * HT * 384;
    qkvln_gemm<<<dim3(784, 6), 256, 0, stream>>>(xc, n1g, n1b, qkv_wb, qkv_b,
                                                 (__hip_bfloat16*)out);
    attn_core<<<12288, 64, 0, stream>>>((const __hip_bfloat16*)out, rpb,
                                        c == 0 ? aoc0 : aoc1, c * 1024);
  }

  // proj + residual -> x1b bf16 (R1) ; fused SE1 -> g1 (R0[38.5:77])
  proj_kernel<<<1568, 256, 0, stream>>>(aoc0, aoc1, proj_wb, proj_b, x, r1b, se1_wb, se1_b, g1);
  // x2 = x1b*sigmoid(g1@se2^T) -> d_out fp32 ; partial LN stats -> R0[0:1.6MB]
  se2_kernel<<<dim3(1568, 2), 256, 0, stream>>>(g1, se2_wb, se2_b, r1b, out, stats);
  // y1 = gelu(LN2(x2) @ c1^T)*bn1 -> R1 (x1b dead)
  c1ln_kernel<<<dim3(1568, 2), 256, 0, stream>>>(out, stats, gc1, S1, bb, bn1g, bn1b, r1b);
  // y2 = gelu(dwconv(y1))*bn2 -> R0 (g1/stats dead)
  dw_kernel<<<1344, 256, 0, stream>>>(r1b, wt, dw_b, bn2g, bn2b, r0b);
  // out = x2 + (y2 @ c2^T)*bn3 -> d_out (in place)
  gemm5_c2<384><<<dim3(1568, 2), 256, 0, stream>>>(r0b, c2_wb, c2_b, bn3g, bn3b, out, out);
}

// Round 18
// 901.202 us; speedup vs baseline: 1.1320x; 1.1320x over previous
//
#include <hip/hip_runtime.h>
#include <hip/hip_bf16.h>

typedef __attribute__((ext_vector_type(4))) float f32x4;
typedef __attribute__((ext_vector_type(8))) __bf16 bf16x8;
typedef __attribute__((ext_vector_type(8))) unsigned short u16x8;

#define SCALE_ 0.17677669529663687f  /* 32^-0.5 */
#define RS 19267584                   /* 50176*384: q/k/v region stride (elems) per chunk */
#define HT 50176                      /* tokens per chunk */

// ---------- workspace layout (bytes) ----------
#define OFF_R1 77070336ull
#define OFF_WB 154140672ull
#define OFF_WT 156205056ull           // f32 [9][384] dw weights
#define OFF_SB 156218880ull           // f32 S1[384] | bb[384]

__device__ __forceinline__ __bf16 tobf(float f) {
  __hip_bfloat16 h = __float2bfloat16(f);
  return __builtin_bit_cast(__bf16, h);
}
__device__ __forceinline__ unsigned short f2u(float f) {
  return __builtin_bit_cast(unsigned short, __float2bfloat16(f));
}

// ---------- fp32 -> bf16 weight copy ----------
__global__ __launch_bounds__(256) void cvt_kernel(const float* __restrict__ src,
                                                  __hip_bfloat16* __restrict__ dst, int n) {
  int i = blockIdx.x * 256 + threadIdx.x;
  int stride = gridDim.x * 256;
  for (; i < n; i += stride) dst[i] = __float2bfloat16(src[i]);
}

// ---------- repack dw weights [384][9] -> [9][384] ----------
__global__ __launch_bounds__(256) void dwrep_kernel(const float* __restrict__ src,
                                                    float* __restrict__ dst) {
  int i = blockIdx.x * 256 + threadIdx.x;
  if (i < 3456) {
    int c = i / 9, k = i - c * 9;
    dst[k * 384 + c] = src[i];
  }
}

// ---------- c1 prep: gc1 = bf16(c1_w * n2g); S1[n] = sum(gc1); bb[n] = c1_b + sum(n2b*c1_w) ----------
__global__ __launch_bounds__(256) void c1prep_kernel(const float* __restrict__ c1w,
                                                     const float* __restrict__ c1b,
                                                     const float* __restrict__ g,
                                                     const float* __restrict__ b,
                                                     __hip_bfloat16* __restrict__ gc1,
                                                     float* __restrict__ S1,
                                                     float* __restrict__ bb) {
  const int n = blockIdx.x * 4 + (threadIdx.x >> 6);
  const int lane = threadIdx.x & 63;
  float s1 = 0.f, sb = 0.f;
  for (int k = lane; k < 384; k += 64) {
    float w = c1w[n * 384 + k];
    __hip_bfloat16 gw = __float2bfloat16(w * g[k]);
    gc1[n * 384 + k] = gw;
    s1 += __bfloat162float(gw);
    sb += w * b[k];
  }
#pragma unroll
  for (int m = 1; m < 64; m <<= 1) { s1 += __shfl_xor(s1, m, 64); sb += __shfl_xor(sb, m, 64); }
  if (lane == 0) { S1[n] = s1; bb[n] = c1b[n] + sb; }
}

// ---------- LayerNorm (one wave per token); WIN: write to rolled+windowed position ----------
template <bool WIN>
__global__ __launch_bounds__(256) void ln_kernel(const float* __restrict__ x,
                                                 const float* __restrict__ gm,
                                                 const float* __restrict__ bt,
                                                 __hip_bfloat16* __restrict__ out) {
  const int tok = blockIdx.x * 4 + (threadIdx.x >> 6);
  const int lane = threadIdx.x & 63;
  const float2* row = (const float2*)(x + (size_t)tok * 384);
  float2 v[3];
  v[0] = row[lane]; v[1] = row[lane + 64]; v[2] = row[lane + 128];
  float s = 0.f, sq = 0.f;
#pragma unroll
  for (int i = 0; i < 3; ++i) { s += v[i].x + v[i].y; sq += v[i].x * v[i].x + v[i].y * v[i].y; }
#pragma unroll
  for (int m = 1; m < 64; m <<= 1) { s += __shfl_xor(s, m, 64); sq += __shfl_xor(sq, m, 64); }
  const float mean = s * (1.f / 384.f);
  const float var = sq * (1.f / 384.f) - mean * mean;
  const float rstd = rsqrtf(var + 1e-5f);
  size_t dst;
  if constexpr (WIN) {
    int b = tok / 3136, l = tok - b * 3136;
    int i = l / 56, j = l - i * 56;
    int hp = i - 3; if (hp < 0) hp += 56;
    int wp = j - 3; if (wp < 0) wp += 56;
    int wi = (hp / 7) * 8 + wp / 7;
    int n = (hp % 7) * 7 + wp % 7;
    dst = (size_t)(b * 64 + wi) * 49 + n;
  } else {
    dst = (size_t)tok;
  }
  unsigned int* o = (unsigned int*)(out + dst * 384);
  const float2* G = (const float2*)gm;
  const float2* Bv = (const float2*)bt;
#pragma unroll
  for (int i = 0; i < 3; ++i) {
    int j = lane + 64 * i;
    float2 gv = G[j], bv = Bv[j];
    float a = (v[i].x - mean) * rstd * gv.x + bv.x;
    float b2 = (v[i].y - mean) * rstd * gv.y + bv.y;
    o[j] = (unsigned)f2u(a) | ((unsigned)f2u(b2) << 16);
  }
}

enum { EPI_C2 = 4, EPI_QKV = 5 };

// ---------- gemm5: occupancy-tuned 64x192 block (NT=3, acc=48 AGPR), LDS-staged ----------
template <int EPI, int KD>
__global__ __launch_bounds__(256) void gemm5(const __hip_bfloat16* __restrict__ Ap,
                                             const __hip_bfloat16* __restrict__ W,
                                             const float* __restrict__ bias,
                                             const float* __restrict__ p0,
                                             const float* __restrict__ p1,
                                             const float* __restrict__ p2,
                                             void* __restrict__ outp) {
  constexpr int KS = KD / 32;
  const int tid = threadIdx.x;
  const int lane = tid & 63, wave = tid >> 6;
  const int g = lane >> 4, r = lane & 15;
  const int row0 = blockIdx.x * 64;
  const int col0 = blockIdx.y * 192;
  const int n0 = wave * 48;

  __shared__ __align__(16) __hip_bfloat16 Al[64][40];
  __shared__ __align__(16) __hip_bfloat16 Bl[192][40];

  const int s_row = tid >> 2, s_c = (tid & 3) * 8;
  const size_t arow = (size_t)(row0 + s_row);

  f32x4 acc[4][3] = {};
  bf16x8 a_reg = *(const bf16x8*)(Ap + arow * KD + s_c);
  bf16x8 b_reg[3];
#pragma unroll
  for (int h = 0; h < 3; ++h)
    b_reg[h] = *(const bf16x8*)(W + (size_t)(col0 + s_row + 64 * h) * KD + s_c);

  for (int kk = 0; kk < KS; ++kk) {
    *(bf16x8*)(&Al[s_row][s_c]) = a_reg;
#pragma unroll
    for (int h = 0; h < 3; ++h) *(bf16x8*)(&Bl[s_row + 64 * h][s_c]) = b_reg[h];
    __syncthreads();
    if (kk + 1 < KS) {
      const int kb = (kk + 1) * 32 + s_c;
      a_reg = *(const bf16x8*)(Ap + arow * KD + kb);
#pragma unroll
      for (int h = 0; h < 3; ++h)
        b_reg[h] = *(const bf16x8*)(W + (size_t)(col0 + s_row + 64 * h) * KD + kb);
    }
    bf16x8 af[4];
#pragma unroll
    for (int mt = 0; mt < 4; ++mt) af[mt] = *(const bf16x8*)(&Al[mt * 16 + r][g * 8]);
#pragma unroll
    for (int nt = 0; nt < 3; ++nt) {
      bf16x8 bf = *(const bf16x8*)(&Bl[n0 + nt * 16 + r][g * 8]);
#pragma unroll
      for (int mt = 0; mt < 4; ++mt)
        acc[mt][nt] = __builtin_amdgcn_mfma_f32_16x16x32_bf16(af[mt], bf, acc[mt][nt], 0, 0, 0);
    }
    __syncthreads();
  }

#pragma unroll
  for (int mt = 0; mt < 4; ++mt) {
#pragma unroll
    for (int j = 0; j < 4; ++j) {
      const int row = row0 + mt * 16 + g * 4 + j;
#pragma unroll
      for (int nt = 0; nt < 3; ++nt) {
        const int col = col0 + n0 + nt * 16 + r;
        float v = acc[mt][nt][j] + bias[col];
        if constexpr (EPI == EPI_QKV) {
          const int s = col / 384, cs = col - s * 384;
          if (s == 0) v *= SCALE_;
          ((__hip_bfloat16*)outp)[(size_t)s * RS + (size_t)row * 384 + cs] = __float2bfloat16(v);
        } else {  // EPI_C2
          float y = v * p0[col] + p1[col];
          ((float*)outp)[(size_t)row * 384 + col] = p2[(size_t)row * 384 + col] + y;
        }
      }
    }
  }
}

// ---------- se2: x2 = x1b*sigmoid(g1@W^T+b), + per-row partial LN stats (deterministic) ----------
__global__ __launch_bounds__(256) void se2_kernel(const __hip_bfloat16* __restrict__ g1,
                                                  const __hip_bfloat16* __restrict__ W,
                                                  const float* __restrict__ bias,
                                                  const __hip_bfloat16* __restrict__ x1b,
                                                  float* __restrict__ x2out,
                                                  float* __restrict__ stats) {
  constexpr int KD = 192;
  const int tid = threadIdx.x;
  const int lane = tid & 63, wave = tid >> 6;
  const int g = lane >> 4, r = lane & 15;
  const int row0 = blockIdx.x * 64;
  const int col0 = blockIdx.y * 192;
  const int n0 = wave * 48;

  __shared__ __align__(16) __hip_bfloat16 Al[64][40];
  __shared__ __align__(16) __hip_bfloat16 Bl[192][40];
  __shared__ float st[512];

  const int s_row = tid >> 2, s_c = (tid & 3) * 8;
  const size_t arow = (size_t)(row0 + s_row);

  f32x4 acc[4][3] = {};
  bf16x8 a_reg = *(const bf16x8*)(g1 + arow * KD + s_c);
  bf16x8 b_reg[3];
#pragma unroll
  for (int h = 0; h < 3; ++h)
    b_reg[h] = *(const bf16x8*)(W + (size_t)(col0 + s_row + 64 * h) * KD + s_c);

  for (int kk = 0; kk < 6; ++kk) {
    *(bf16x8*)(&Al[s_row][s_c]) = a_reg;
#pragma unroll
    for (int h = 0; h < 3; ++h) *(bf16x8*)(&Bl[s_row + 64 * h][s_c]) = b_reg[h];
    __syncthreads();
    if (kk + 1 < 6) {
      const int kb = (kk + 1) * 32 + s_c;
      a_reg = *(const bf16x8*)(g1 + arow * KD + kb);
#pragma unroll
      for (int h = 0; h < 3; ++h)
        b_reg[h] = *(const bf16x8*)(W + (size_t)(col0 + s_row + 64 * h) * KD + kb);
    }
    bf16x8 af[4];
#pragma unroll
    for (int mt = 0; mt < 4; ++mt) af[mt] = *(const bf16x8*)(&Al[mt * 16 + r][g * 8]);
#pragma unroll
    for (int nt = 0; nt < 3; ++nt) {
      bf16x8 bf = *(const bf16x8*)(&Bl[n0 + nt * 16 + r][g * 8]);
#pragma unroll
      for (int mt = 0; mt < 4; ++mt)
        acc[mt][nt] = __builtin_amdgcn_mfma_f32_16x16x32_bf16(af[mt], bf, acc[mt][nt], 0, 0, 0);
    }
    __syncthreads();
  }

#pragma unroll
  for (int mt = 0; mt < 4; ++mt) {
#pragma unroll
    for (int j = 0; j < 4; ++j) {
      const int lrow = mt * 16 + g * 4 + j;
      const size_t ob = (size_t)(row0 + lrow) * 384;
      float s = 0.f, sq = 0.f;
#pragma unroll
      for (int nt = 0; nt < 3; ++nt) {
        const int col = col0 + n0 + nt * 16 + r;
        float v = acc[mt][nt][j] + bias[col];
        float gate = 1.f / (1.f + __expf(-v));
        float x1v = __bfloat162float(x1b[ob + col]);
        float x2 = x1v * gate;
        x2out[ob + col] = x2;
        s += x2; sq += x2 * x2;
      }
#pragma unroll
      for (int m = 1; m < 16; m <<= 1) { s += __shfl_xor(s, m, 64); sq += __shfl_xor(sq, m, 64); }
      if (r == 0) { st[wave * 128 + lrow] = s; st[wave * 128 + 64 + lrow] = sq; }
    }
  }
  __syncthreads();
  if (tid < 64) {
    float s = st[tid] + st[128 + tid] + st[256 + tid] + st[384 + tid];
    float sq = st[64 + tid] + st[192 + tid] + st[320 + tid] + st[448 + tid];
    stats[(size_t)(row0 + tid) * 4 + blockIdx.y * 2] = s;
    stats[(size_t)(row0 + tid) * 4 + blockIdx.y * 2 + 1] = sq;
  }
}

// ---------- c1ln: y1 = gelu(LN2(x2) @ c1^T)*bn1+bn1b with LN folded (gc1/S1/bb) ----------
__global__ __launch_bounds__(256) void c1ln_kernel(const float* __restrict__ x2,
                                                   const float* __restrict__ stats,
                                                   const __hip_bfloat16* __restrict__ gc1,
                                                   const float* __restrict__ S1,
                                                   const float* __restrict__ bb,
                                                   const float* __restrict__ bn1g_,
                                                   const float* __restrict__ bn1b_,
                                                   __hip_bfloat16* __restrict__ y1) {
  const int tid = threadIdx.x;
  const int lane = tid & 63, wave = tid >> 6;
  const int g = lane >> 4, r = lane & 15;
  const int row0 = blockIdx.x * 64;
  const int col0 = blockIdx.y * 192;
  const int n0 = wave * 48;

  __shared__ __align__(16) __hip_bfloat16 Al[64][40];
  __shared__ __align__(16) __hip_bfloat16 Bl[192][40];
  __shared__ float mean_l[64], rstd_l[64];

  const int s_row = tid >> 2, s_c = (tid & 3) * 8;
  const size_t abase = (size_t)(row0 + s_row) * 384;

  if (tid < 64) {
    const size_t row = row0 + tid;
    float s = stats[row * 4] + stats[row * 4 + 2];
    float sq = stats[row * 4 + 1] + stats[row * 4 + 3];
    float mean = s * (1.f / 384.f);
    float var = sq * (1.f / 384.f) - mean * mean;
    mean_l[tid] = mean;
    rstd_l[tid] = rsqrtf(var + 1e-5f);
  }

  f32x4 acc[4][3] = {};
  bf16x8 a_reg;
  {
    const float4* sp = (const float4*)(x2 + abase + s_c);
    float4 a = sp[0], b = sp[1];
    a_reg[0] = tobf(a.x); a_reg[1] = tobf(a.y); a_reg[2] = tobf(a.z); a_reg[3] = tobf(a.w);
    a_reg[4] = tobf(b.x); a_reg[5] = tobf(b.y); a_reg[6] = tobf(b.z); a_reg[7] = tobf(b.w);
  }
  bf16x8 b_reg[3];
#pragma unroll
  for (int h = 0; h < 3; ++h)
    b_reg[h] = *(const bf16x8*)(gc1 + (size_t)(col0 + s_row + 64 * h) * 384 + s_c);

  for (int kk = 0; kk < 12; ++kk) {
    *(bf16x8*)(&Al[s_row][s_c]) = a_reg;
#pragma unroll
    for (int h = 0; h < 3; ++h) *(bf16x8*)(&Bl[s_row + 64 * h][s_c]) = b_reg[h];
    __syncthreads();
    if (kk + 1 < 12) {
      const int kb = (kk + 1) * 32 + s_c;
      const float4* sp = (const float4*)(x2 + abase + kb);
      float4 a = sp[0], b = sp[1];
      a_reg[0] = tobf(a.x); a_reg[1] = tobf(a.y); a_reg[2] = tobf(a.z); a_reg[3] = tobf(a.w);
      a_reg[4] = tobf(b.x); a_reg[5] = tobf(b.y); a_reg[6] = tobf(b.z); a_reg[7] = tobf(b.w);
#pragma unroll
      for (int h = 0; h < 3; ++h)
        b_reg[h] = *(const bf16x8*)(gc1 + (size_t)(col0 + s_row + 64 * h) * 384 + kb);
    }
    bf16x8 af[4];
#pragma unroll
    for (int mt = 0; mt < 4; ++mt) af[mt] = *(const bf16x8*)(&Al[mt * 16 + r][g * 8]);
#pragma unroll
    for (int nt = 0; nt < 3; ++nt) {
      bf16x8 bf = *(const bf16x8*)(&Bl[n0 + nt * 16 + r][g * 8]);
#pragma unroll
      for (int mt = 0; mt < 4; ++mt)
        acc[mt][nt] = __builtin_amdgcn_mfma_f32_16x16x32_bf16(af[mt], bf, acc[mt][nt], 0, 0, 0);
    }
    __syncthreads();
  }

#pragma unroll
  for (int mt = 0; mt < 4; ++mt) {
#pragma unroll
    for (int j = 0; j < 4; ++j) {
      const int rl = mt * 16 + g * 4 + j;
      const int row = row0 + rl;
      const float mean = mean_l[rl], rstd = rstd_l[rl];
#pragma unroll
      for (int nt = 0; nt < 3; ++nt) {
        const int col = col0 + n0 + nt * 16 + r;
        float v = rstd * (acc[mt][nt][j] - mean * S1[col]) + bb[col];
        float gl = 0.5f * v * (1.f + erff(v * 0.70710678118654752f));
        y1[(size_t)row * 384 + col] = __float2bfloat16(gl * bn1g_[col] + bn1b_[col]);
      }
    }
  }
}

// ---------- proj: x1 = x + proj(ao); x1 -> bf16 only; fused SE1 -> g1 ----------
__global__ __launch_bounds__(256) void proj_kernel(const __hip_bfloat16* __restrict__ aoc0,
                                                   const __hip_bfloat16* __restrict__ aoc1,
                                                   const __hip_bfloat16* __restrict__ W,
                                                   const float* __restrict__ bias,
                                                   const float* __restrict__ x,
                                                   __hip_bfloat16* __restrict__ x1b,
                                                   const __hip_bfloat16* __restrict__ W2,
                                                   const float* __restrict__ bias2,
                                                   __hip_bfloat16* __restrict__ g1) {
  constexpr int NT = 6;
  const int tid = threadIdx.x;
  const int lane = tid & 63, wave = tid >> 6;
  const int g = lane >> 4, r = lane & 15;
  const int row0 = blockIdx.x * 64;
  const int n0 = wave * 96;

  __shared__ __align__(16) char smem[50176];
  auto Al = (__hip_bfloat16(*)[40])smem;
  auto Bl = (__hip_bfloat16(*)[40])(smem + 64 * 80);

  const int s_row = tid >> 2;
  const int s_c = (tid & 3) * 8;

  const __hip_bfloat16* ap;
  {
    int t = row0 + s_row;
    int b = t / 3136, l = t - b * 3136;
    int i = l / 56, j = l - i * 56;
    int hp = i >= 3 ? i - 3 : i + 53;
    int wp = j >= 3 ? j - 3 : j + 53;
    size_t arow = ((size_t)(b * 64 + (hp / 7) * 8 + wp / 7)) * 49 + (hp % 7) * 7 + (wp % 7);
    ap = (arow < (size_t)HT) ? (aoc0 + arow * 384) : (aoc1 + (arow - HT) * 384);
  }

  f32x4 acc[4][NT] = {};

  bf16x8 a_reg = *(const bf16x8*)(ap + s_c);
  bf16x8 b_reg[NT];
#pragma unroll
  for (int h = 0; h < NT; ++h)
    b_reg[h] = *(const bf16x8*)(W + (size_t)(s_row + 64 * h) * 384 + s_c);

  for (int kk = 0; kk < 12; ++kk) {
    *(bf16x8*)(&Al[s_row][s_c]) = a_reg;
#pragma unroll
    for (int h = 0; h < NT; ++h) *(bf16x8*)(&Bl[s_row + 64 * h][s_c]) = b_reg[h];
    __syncthreads();
    if (kk + 1 < 12) {
      const int kb = (kk + 1) * 32 + s_c;
      a_reg = *(const bf16x8*)(ap + kb);
#pragma unroll
      for (int h = 0; h < NT; ++h)
        b_reg[h] = *(const bf16x8*)(W + (size_t)(s_row + 64 * h) * 384 + kb);
    }
    bf16x8 af[4];
#pragma unroll
    for (int mt = 0; mt < 4; ++mt) af[mt] = *(const bf16x8*)(&Al[mt * 16 + r][g * 8]);
#pragma unroll
    for (int nt = 0; nt < NT; ++nt) {
      bf16x8 bf = *(const bf16x8*)(&Bl[n0 + nt * 16 + r][g * 8]);
#pragma unroll
      for (int mt = 0; mt < 4; ++mt)
        acc[mt][nt] = __builtin_amdgcn_mfma_f32_16x16x32_bf16(af[mt], bf, acc[mt][nt], 0, 0, 0);
    }
    __syncthreads();
  }

  auto Xt = (__hip_bfloat16(*)[392])smem;
#pragma unroll
  for (int mt = 0; mt < 4; ++mt)
#pragma unroll
    for (int j = 0; j < 4; ++j) {
      const int lrow = mt * 16 + g * 4 + j;
      const size_t ob = (size_t)(row0 + lrow) * 384;
#pragma unroll
      for (int nt = 0; nt < NT; ++nt) {
        const int col = n0 + nt * 16 + r;
        float v = acc[mt][nt][j] + bias[col] + x[ob + col];
        __hip_bfloat16 hb = __float2bfloat16(v);
        x1b[ob + col] = hb;
        Xt[lrow][col] = hb;
      }
    }
  __syncthreads();
  f32x4 acc2[4][3] = {};
  const int c0 = wave * 48;
  for (int kk = 0; kk < 12; ++kk) {
    bf16x8 af2[4];
#pragma unroll
    for (int mt = 0; mt < 4; ++mt)
      af2[mt] = *(const bf16x8*)(&Xt[mt * 16 + r][kk * 32 + g * 8]);
#pragma unroll
    for (int nt2 = 0; nt2 < 3; ++nt2) {
      bf16x8 b2 = *(const bf16x8*)(W2 + (size_t)(c0 + nt2 * 16 + r) * 384 + kk * 32 + g * 8);
#pragma unroll
      for (int mt = 0; mt < 4; ++mt)
        acc2[mt][nt2] = __builtin_amdgcn_mfma_f32_16x16x32_bf16(af2[mt], b2, acc2[mt][nt2], 0, 0, 0);
    }
  }
#pragma unroll
  for (int mt = 0; mt < 4; ++mt)
#pragma unroll
    for (int j = 0; j < 4; ++j) {
      const size_t row = row0 + mt * 16 + g * 4 + j;
#pragma unroll
      for (int nt2 = 0; nt2 < 3; ++nt2) {
        const int col2 = c0 + nt2 * 16 + r;
        float v = acc2[mt][nt2][j] + bias2[col2];
        g1[row * 192 + col2] = __float2bfloat16(fmaxf(v, 0.f));
      }
    }
}

// ---------- attention core: one 64-thread block per (window, head); ao chunk-local ----------
__global__ __launch_bounds__(64) void attn_core(const __hip_bfloat16* __restrict__ qkv,
                                                const float* __restrict__ rpb,
                                                __hip_bfloat16* __restrict__ ao, int win0) {
  const int bid = blockIdx.x;
  const int win_l = bid / 12, head = bid - win_l * 12;
  const int widx = (win0 + win_l) & 63;
  const int lane = threadIdx.x;
  const int g = lane >> 4, r = lane & 15;
  const int wbh = (widx >> 3) * 7, wbw = (widx & 7) * 7;
  const size_t rowbase = (size_t)(win_l * 49) * 384 + head * 32;
  const __hip_bfloat16* q_g = qkv + rowbase;
  const __hip_bfloat16* k_g = qkv + RS + rowbase;
  const __hip_bfloat16* v_g = qkv + 2 * RS + rowbase;

  __shared__ __align__(16) __hip_bfloat16 P_l[49 * 64];
  __shared__ __align__(16) unsigned short vT[32 * 72];

  bf16x8 zf;
#pragma unroll
  for (int i = 0; i < 8; ++i) zf[i] = tobf(0.f);

  for (int i = lane; i < 512; i += 64) {
    int d = i >> 4, t = 48 + (i & 15);
    vT[d * 72 + t] = 0;
  }
  if (lane < 49) {
#pragma unroll
    for (int c = 0; c < 4; ++c) {
      u16x8 vv = *(const u16x8*)(v_g + (size_t)lane * 384 + c * 8);
#pragma unroll
      for (int e = 0; e < 8; ++e) vT[(c * 8 + e) * 72 + lane] = vv[e];
    }
  }

  int yj4[4], xj4[4], rj4[4];
  bool val4[4];
#pragma unroll
  for (int nt = 0; nt < 4; ++nt) {
    int jt = nt * 16 + r;
    val4[nt] = jt < 49;
    int jc = val4[nt] ? jt : 0;
    int yj = jc / 7, xj = jc - yj * 7;
    yj4[nt] = yj; xj4[nt] = xj;
    int hj = wbh + yj, wj = wbw + xj;
    rj4[nt] = (hj < 49 ? 0 : (hj < 53 ? 1 : 2)) * 3 + (wj < 49 ? 0 : (wj < 53 ? 1 : 2));
  }

  f32x4 sA[4][4] = {};
  {
    bf16x8 qa[4];
#pragma unroll
    for (int mt = 0; mt < 4; ++mt) {
      int row = mt * 16 + r;
      qa[mt] = (row < 49) ? *(const bf16x8*)(q_g + (size_t)row * 384 + g * 8) : zf;
    }
#pragma unroll
    for (int nt = 0; nt < 4; ++nt) {
      int rowk = nt * 16 + r;
      bf16x8 kf = (rowk < 49) ? *(const bf16x8*)(k_g + (size_t)rowk * 384 + g * 8) : zf;
#pragma unroll
      for (int mt = 0; mt < 4; ++mt)
        sA[mt][nt] = __builtin_amdgcn_mfma_f32_16x16x32_bf16(qa[mt], kf, sA[mt][nt], 0, 0, 0);
    }
  }
#pragma unroll
  for (int mt = 0; mt < 4; ++mt) {
#pragma unroll
    for (int j = 0; j < 4; ++j) {
      const int it = mt * 16 + g * 4 + j;
      if (it < 49) {
        int yi = it / 7, xi = it - yi * 7;
        int hi = wbh + yi, wi2 = wbw + xi;
        int ri = (hi < 49 ? 0 : (hi < 53 ? 1 : 2)) * 3 + (wi2 < 49 ? 0 : (wi2 < 53 ? 1 : 2));
        float v4[4];
#pragma unroll
        for (int nt = 0; nt < 4; ++nt) {
          float sv = -1e30f;
          if (val4[nt]) {
            sv = sA[mt][nt][j] + rpb[((yi - yj4[nt] + 6) * 13 + (xi - xj4[nt] + 6)) * 12 + head];
            if (ri != rj4[nt]) sv -= 100.f;
          }
          v4[nt] = sv;
        }
        float mx = fmaxf(fmaxf(v4[0], v4[1]), fmaxf(v4[2], v4[3]));
#pragma unroll
        for (int m = 1; m < 16; m <<= 1) mx = fmaxf(mx, __shfl_xor(mx, m, 64));
        float sum = 0.f;
#pragma unroll
        for (int nt = 0; nt < 4; ++nt) { v4[nt] = __expf(v4[nt] - mx); sum += v4[nt]; }
#pragma unroll
        for (int m = 1; m < 16; m <<= 1) sum += __shfl_xor(sum, m, 64);
        float inv = 1.f / sum;
#pragma unroll
        for (int nt = 0; nt < 4; ++nt) {
          int col = nt * 16 + r;
          int swz = ((col >> 3) ^ (it & 7));
          P_l[it * 64 + swz * 8 + (col & 7)] = __float2bfloat16(v4[nt] * inv);
        }
      }
    }
  }
  f32x4 oA[4][2] = {};
#pragma unroll
  for (int ks = 0; ks < 2; ++ks) {
    bf16x8 pa[4];
#pragma unroll
    for (int mt = 0; mt < 4; ++mt) {
      int row = mt * 16 + r;
      int swz = (ks * 4 + g) ^ (row & 7);
      pa[mt] = (row < 49) ? *(const bf16x8*)(&P_l[row * 64 + swz * 8]) : zf;
    }
#pragma unroll
    for (int nt = 0; nt < 2; ++nt) {
      bf16x8 vbv = *(const bf16x8*)(&vT[(nt * 16 + r) * 72 + ks * 32 + g * 8]);
#pragma unroll
      for (int mt = 0; mt < 4; ++mt)
        oA[mt][nt] = __builtin_amdgcn_mfma_f32_16x16x32_bf16(pa[mt], vbv, oA[mt][nt], 0, 0, 0);
    }
  }
#pragma unroll
  for (int mt = 0; mt < 4; ++mt)
#pragma unroll
    for (int nt = 0; nt < 2; ++nt)
#pragma unroll
      for (int j = 0; j < 4; ++j) {
        int row = mt * 16 + g * 4 + j;
        if (row < 49)
          ao[((size_t)win_l * 49 + row) * 384 + head * 32 + nt * 16 + r] =
              __float2bfloat16(oA[mt][nt][j]);
      }
}

// ---------- depthwise 3x3 (NHWC) + gelu*bn2 ----------
__global__ __launch_bounds__(256) void dw_kernel(const __hip_bfloat16* __restrict__ y1,
                                                 const float* __restrict__ wt,
                                                 const float* __restrict__ wb,
                                                 const float* __restrict__ g2,
                                                 const float* __restrict__ b2,
                                                 __hip_bfloat16* __restrict__ y2) {
  const int tid = blockIdx.x * 256 + threadIdx.x;
  const int c8 = tid % 48;
  int t = tid / 48;
  const int q = t & 3; t >>= 2;
  const int hq = t % 56;
  const int b = t / 56;
  const int cb = c8 * 8;
  const int x0 = q * 14;

  float wr[9][8];
#pragma unroll
  for (int k = 0; k < 9; ++k) {
    float4 a = *(const float4*)(wt + k * 384 + cb);
    float4 c = *(const float4*)(wt + k * 384 + cb + 4);
    wr[k][0] = a.x; wr[k][1] = a.y; wr[k][2] = a.z; wr[k][3] = a.w;
    wr[k][4] = c.x; wr[k][5] = c.y; wr[k][6] = c.z; wr[k][7] = c.w;
  }
  if (hq == 0) {
#pragma unroll
    for (int k = 0; k < 3; ++k)
#pragma unroll
      for (int i = 0; i < 8; ++i) wr[k][i] = 0.f;
  }
  if (hq == 55) {
#pragma unroll
    for (int k = 6; k < 9; ++k)
#pragma unroll
      for (int i = 0; i < 8; ++i) wr[k][i] = 0.f;
  }
  float bias[8], gv[8], bv[8];
  {
    float4 a = *(const float4*)(wb + cb), c = *(const float4*)(wb + cb + 4);
    bias[0] = a.x; bias[1] = a.y; bias[2] = a.z; bias[3] = a.w;
    bias[4] = c.x; bias[5] = c.y; bias[6] = c.z; bias[7] = c.w;
    float4 d = *(const float4*)(g2 + cb), e = *(const float4*)(g2 + cb + 4);
    gv[0] = d.x; gv[1] = d.y; gv[2] = d.z; gv[3] = d.w;
    gv[4] = e.x; gv[5] = e.y; gv[6] = e.z; gv[7] = e.w;
    float4 f = *(const float4*)(b2 + cb), h = *(const float4*)(b2 + cb + 4);
    bv[0] = f.x; bv[1] = f.y; bv[2] = f.z; bv[3] = f.w;
    bv[4] = h.x; bv[5] = h.y; bv[6] = h.z; bv[7] = h.w;
  }
  const int hm = hq > 0 ? hq - 1 : 0;
  const int hp = hq < 55 ? hq + 1 : 55;
  const __hip_bfloat16* r0 = y1 + ((size_t)(b * 3136 + hm * 56)) * 384 + cb;
  const __hip_bfloat16* r1 = y1 + ((size_t)(b * 3136 + hq * 56)) * 384 + cb;
  const __hip_bfloat16* r2 = y1 + ((size_t)(b * 3136 + hp * 56)) * 384 + cb;
  __hip_bfloat16* op = y2 + ((size_t)(b * 3136 + hq * 56)) * 384 + cb;

  u16x8 zv;
#pragma unroll
  for (int i = 0; i < 8; ++i) zv[i] = 0;
#define LDC(rp, x) (((unsigned)(x) < 56u) ? *(const u16x8*)((rp) + (size_t)(x) * 384) : zv)

  u16x8 L0 = LDC(r0, x0 - 1), L1 = LDC(r1, x0 - 1), L2 = LDC(r2, x0 - 1);
  u16x8 C0 = LDC(r0, x0), C1 = LDC(r1, x0), C2 = LDC(r2, x0);
#pragma unroll
  for (int xi = 0; xi < 14; ++xi) {
    const int x = x0 + xi;
    u16x8 R0 = LDC(r0, x + 1), R1 = LDC(r1, x + 1), R2 = LDC(r2, x + 1);
    float acc[8];
#pragma unroll
    for (int i = 0; i < 8; ++i) acc[i] = bias[i];
#pragma unroll
    for (int i = 0; i < 8; ++i) {
      acc[i] += __uint_as_float((unsigned)L0[i] << 16) * wr[0][i];
      acc[i] += __uint_as_float((unsigned)C0[i] << 16) * wr[1][i];
      acc[i] += __uint_as_float((unsigned)R0[i] << 16) * wr[2][i];
      acc[i] += __uint_as_float((unsigned)L1[i] << 16) * wr[3][i];
      acc[i] += __uint_as_float((unsigned)C1[i] << 16) * wr[4][i];
      acc[i] += __uint_as_float((unsigned)R1[i] << 16) * wr[5][i];
      acc[i] += __uint_as_float((unsigned)L2[i] << 16) * wr[6][i];
      acc[i] += __uint_as_float((unsigned)C2[i] << 16) * wr[7][i];
      acc[i] += __uint_as_float((unsigned)R2[i] << 16) * wr[8][i];
    }
    u16x8 o;
#pragma unroll
    for (int i = 0; i < 8; ++i) {
      float u = acc[i];
      float gl = 0.5f * u * (1.f + erff(u * 0.70710678118654752f));
      o[i] = f2u(gl * gv[i] + bv[i]);
    }
    *(u16x8*)(op + (size_t)x * 384) = o;
    L0 = C0; L1 = C1; L2 = C2;
    C0 = R0; C1 = R1; C2 = R2;
  }
#undef LDC
}

extern "C" void kernel_launch(void* const* d_in, const int* in_sizes, int n_in, void* d_out,
                              int out_size, void* d_ws, size_t ws_size, hipStream_t stream) {
  (void)in_sizes; (void)n_in; (void)out_size; (void)ws_size;
  const float* x = (const float*)d_in[0];
  const float* n1g = (const float*)d_in[1];
  const float* n1b = (const float*)d_in[2];
  const float* qkv_w = (const float*)d_in[3];
  const float* qkv_b = (const float*)d_in[4];
  const float* rpb = (const float*)d_in[5];
  const float* proj_w = (const float*)d_in[6];
  const float* proj_b = (const float*)d_in[7];
  const float* se1_w = (const float*)d_in[8];
  const float* se1_b = (const float*)d_in[9];
  const float* se2_w = (const float*)d_in[10];
  const float* se2_b = (const float*)d_in[11];
  const float* n2g = (const float*)d_in[12];
  const float* n2b = (const float*)d_in[13];
  const float* c1_w = (const float*)d_in[14];
  const float* c1_b = (const float*)d_in[15];
  const float* bn1g = (const float*)d_in[16];
  const float* bn1b = (const float*)d_in[17];
  const float* dw_w = (const float*)d_in[18];
  const float* dw_b = (const float*)d_in[19];
  const float* bn2g = (const float*)d_in[20];
  const float* bn2b = (const float*)d_in[21];
  const float* c2_w = (const float*)d_in[22];
  const float* c2_b = (const float*)d_in[23];
  const float* bn3g = (const float*)d_in[24];
  const float* bn3b = (const float*)d_in[25];

  char* ws = (char*)d_ws;
  __hip_bfloat16* r0b = (__hip_bfloat16*)ws;              // R0: xn -> aoc1/stats/g1 -> y2
  __hip_bfloat16* r1b = (__hip_bfloat16*)(ws + OFF_R1);   // R1: x1b -> y1
  __hip_bfloat16* wbp = (__hip_bfloat16*)(ws + OFF_WB);
  float* wt = (float*)(ws + OFF_WT);
  float* S1 = (float*)(ws + OFF_SB);
  float* bb = S1 + 384;
  __hip_bfloat16* qkv_wb = wbp;             // 442368
  __hip_bfloat16* proj_wb = wbp + 442368;   // 147456
  __hip_bfloat16* se1_wb = wbp + 589824;    // 73728
  __hip_bfloat16* se2_wb = wbp + 663552;    // 73728
  __hip_bfloat16* gc1 = wbp + 737280;       // 147456 (c1_w * n2g, bf16)
  __hip_bfloat16* c2_wb = wbp + 884736;     // 147456
  float* out = (float*)d_out;

  // chunked ao locations
  __hip_bfloat16* aoc0 = (__hip_bfloat16*)d_out + 3 * RS;  // d_out tail (after qkv scratch)
  __hip_bfloat16* aoc1 = r0b;                              // R0[0:38.5MB]
  __hip_bfloat16* g1 = r0b + (size_t)HT * 384;             // R0[38.5:77MB]
  float* stats = (float*)r0b;                              // R0[0:1.6MB] (after proj done)

  cvt_kernel<<<1728, 256, 0, stream>>>(qkv_w, qkv_wb, 442368);
  cvt_kernel<<<576, 256, 0, stream>>>(proj_w, proj_wb, 147456);
  cvt_kernel<<<288, 256, 0, stream>>>(se1_w, se1_wb, 73728);
  cvt_kernel<<<288, 256, 0, stream>>>(se2_w, se2_wb, 73728);
  cvt_kernel<<<576, 256, 0, stream>>>(c2_w, c2_wb, 147456);
  c1prep_kernel<<<96, 256, 0, stream>>>(c1_w, c1_b, n2g, n2b, gc1, S1, bb);
  dwrep_kernel<<<14, 256, 0, stream>>>(dw_w, wt);

  // LN1 + shift + window partition -> xn (R0, bf16, windowed)
  ln_kernel<true><<<25088, 256, 0, stream>>>(x, n1g, n1b, r0b);

  // attention: 2 chunks; qkv -> d_out[0:115.6MB]; ao: chunk0 -> d_out tail, chunk1 -> R0[0:38.5]
  for (int c = 0; c < 2; ++c) {
    const __hip_bfloat16* xa = r0b + (size_t)c * HT * 384;
    gemm5<EPI_QKV, 384><<<dim3(784, 6), 256, 0, stream>>>(
        xa, qkv_wb, qkv_b, nullptr, nullptr, nullptr, out);
    attn_core<<<12288, 64, 0, stream>>>((const __hip_bfloat16*)out, rpb,
                                        c == 0 ? aoc0 : aoc1, c * 1024);
  }

  // proj + residual -> x1b bf16 (R1) ; fused SE1 -> g1 (R0[38.5:77])
  proj_kernel<<<1568, 256, 0, stream>>>(aoc0, aoc1, proj_wb, proj_b, x, r1b, se1_wb, se1_b, g1);
  // x2 = x1b*sigmoid(g1@se2^T) -> d_out fp32 ; partial LN stats -> R0[0:1.6MB]
  se2_kernel<<<dim3(1568, 2), 256, 0, stream>>>(g1, se2_wb, se2_b, r1b, out, stats);
  // y1 = gelu(LN2(x2) @ c1^T)*bn1 -> R1 (x1b dead)
  c1ln_kernel<<<dim3(1568, 2), 256, 0, stream>>>(out, stats, gc1, S1, bb, bn1g, bn1b, r1b);
  // y2 = gelu(dwconv(y1))*bn2 -> R0 (g1/stats dead)
  dw_kernel<<<1344, 256, 0, stream>>>(r1b, wt, dw_b, bn2g, bn2b, r0b);
  // out = x2 + (y2 @ c2^T)*bn3 -> d_out (in place)
  gemm5<EPI_C2, 384><<<dim3(1568, 2), 256, 0, stream>>>(
      r0b, c2_wb, c2_b, bn3g, bn3b, out, out);
}

// Round 19
// 824.547 us; speedup vs baseline: 1.2372x; 1.0930x over previous
//
#include <hip/hip_runtime.h>
#include <hip/hip_bf16.h>

typedef __attribute__((ext_vector_type(4))) float f32x4;
typedef __attribute__((ext_vector_type(8))) __bf16 bf16x8;
typedef __attribute__((ext_vector_type(8))) unsigned short u16x8;

#define SCALE_ 0.17677669529663687f  /* 32^-0.5 */
#define RS 19267584                   /* 50176*384: q/k/v region stride (elems) per chunk */
#define HT 50176                      /* tokens per chunk */

// ---------- workspace layout (bytes) ----------
#define OFF_R1 77070336ull
#define OFF_WB 154140672ull
#define OFF_WT 156205056ull           // f32 [9][384] dw weights
#define OFF_SB 156218880ull           // f32 S1[384] | bb[384]

__device__ __forceinline__ __bf16 tobf(float f) {
  __hip_bfloat16 h = __float2bfloat16(f);
  return __builtin_bit_cast(__bf16, h);
}
__device__ __forceinline__ unsigned short f2u(float f) {
  return __builtin_bit_cast(unsigned short, __float2bfloat16(f));
}

// ---------- fp32 -> bf16 weight copy ----------
__global__ __launch_bounds__(256) void cvt_kernel(const float* __restrict__ src,
                                                  __hip_bfloat16* __restrict__ dst, int n) {
  int i = blockIdx.x * 256 + threadIdx.x;
  int stride = gridDim.x * 256;
  for (; i < n; i += stride) dst[i] = __float2bfloat16(src[i]);
}

// ---------- repack dw weights [384][9] -> [9][384] ----------
__global__ __launch_bounds__(256) void dwrep_kernel(const float* __restrict__ src,
                                                    float* __restrict__ dst) {
  int i = blockIdx.x * 256 + threadIdx.x;
  if (i < 3456) {
    int c = i / 9, k = i - c * 9;
    dst[k * 384 + c] = src[i];
  }
}

// ---------- c1 prep: gc1 = bf16(c1_w * n2g); S1[n] = sum(gc1); bb[n] = c1_b + sum(n2b*c1_w) ----------
__global__ __launch_bounds__(256) void c1prep_kernel(const float* __restrict__ c1w,
                                                     const float* __restrict__ c1b,
                                                     const float* __restrict__ g,
                                                     const float* __restrict__ b,
                                                     __hip_bfloat16* __restrict__ gc1,
                                                     float* __restrict__ S1,
                                                     float* __restrict__ bb) {
  const int n = blockIdx.x * 4 + (threadIdx.x >> 6);
  const int lane = threadIdx.x & 63;
  float s1 = 0.f, sb = 0.f;
  for (int k = lane; k < 384; k += 64) {
    float w = c1w[n * 384 + k];
    __hip_bfloat16 gw = __float2bfloat16(w * g[k]);
    gc1[n * 384 + k] = gw;
    s1 += __bfloat162float(gw);
    sb += w * b[k];
  }
#pragma unroll
  for (int m = 1; m < 64; m <<= 1) { s1 += __shfl_xor(s1, m, 64); sb += __shfl_xor(sb, m, 64); }
  if (lane == 0) { S1[n] = s1; bb[n] = c1b[n] + sb; }
}

// ---------- LayerNorm (one wave per token); WIN: write to rolled+windowed position ----------
template <bool WIN>
__global__ __launch_bounds__(256) void ln_kernel(const float* __restrict__ x,
                                                 const float* __restrict__ gm,
                                                 const float* __restrict__ bt,
                                                 __hip_bfloat16* __restrict__ out) {
  const int tok = blockIdx.x * 4 + (threadIdx.x >> 6);
  const int lane = threadIdx.x & 63;
  const float2* row = (const float2*)(x + (size_t)tok * 384);
  float2 v[3];
  v[0] = row[lane]; v[1] = row[lane + 64]; v[2] = row[lane + 128];
  float s = 0.f, sq = 0.f;
#pragma unroll
  for (int i = 0; i < 3; ++i) { s += v[i].x + v[i].y; sq += v[i].x * v[i].x + v[i].y * v[i].y; }
#pragma unroll
  for (int m = 1; m < 64; m <<= 1) { s += __shfl_xor(s, m, 64); sq += __shfl_xor(sq, m, 64); }
  const float mean = s * (1.f / 384.f);
  const float var = sq * (1.f / 384.f) - mean * mean;
  const float rstd = rsqrtf(var + 1e-5f);
  size_t dst;
  if constexpr (WIN) {
    int b = tok / 3136, l = tok - b * 3136;
    int i = l / 56, j = l - i * 56;
    int hp = i - 3; if (hp < 0) hp += 56;
    int wp = j - 3; if (wp < 0) wp += 56;
    int wi = (hp / 7) * 8 + wp / 7;
    int n = (hp % 7) * 7 + wp % 7;
    dst = (size_t)(b * 64 + wi) * 49 + n;
  } else {
    dst = (size_t)tok;
  }
  unsigned int* o = (unsigned int*)(out + dst * 384);
  const float2* G = (const float2*)gm;
  const float2* Bv = (const float2*)bt;
#pragma unroll
  for (int i = 0; i < 3; ++i) {
    int j = lane + 64 * i;
    float2 gv = G[j], bv = Bv[j];
    float a = (v[i].x - mean) * rstd * gv.x + bv.x;
    float b2 = (v[i].y - mean) * rstd * gv.y + bv.y;
    o[j] = (unsigned)f2u(a) | ((unsigned)f2u(b2) << 16);
  }
}

// ---------- gemm5 QKV: occupancy-tuned 64x192 block (NT=3, acc=48 AGPR), LDS-staged ----------
__global__ __launch_bounds__(256) void qkv_gemm5(const __hip_bfloat16* __restrict__ Ap,
                                                 const __hip_bfloat16* __restrict__ W,
                                                 const float* __restrict__ bias,
                                                 __hip_bfloat16* __restrict__ outp) {
  const int tid = threadIdx.x;
  const int lane = tid & 63, wave = tid >> 6;
  const int g = lane >> 4, r = lane & 15;
  const int row0 = blockIdx.x * 64;
  const int col0 = blockIdx.y * 192;
  const int n0 = wave * 48;

  __shared__ __align__(16) __hip_bfloat16 Al[64][40];
  __shared__ __align__(16) __hip_bfloat16 Bl[192][40];

  const int s_row = tid >> 2, s_c = (tid & 3) * 8;
  const size_t arow = (size_t)(row0 + s_row);

  f32x4 acc[4][3] = {};
  bf16x8 a_reg = *(const bf16x8*)(Ap + arow * 384 + s_c);
  bf16x8 b_reg[3];
#pragma unroll
  for (int h = 0; h < 3; ++h)
    b_reg[h] = *(const bf16x8*)(W + (size_t)(col0 + s_row + 64 * h) * 384 + s_c);

  for (int kk = 0; kk < 12; ++kk) {
    *(bf16x8*)(&Al[s_row][s_c]) = a_reg;
#pragma unroll
    for (int h = 0; h < 3; ++h) *(bf16x8*)(&Bl[s_row + 64 * h][s_c]) = b_reg[h];
    __syncthreads();
    if (kk + 1 < 12) {
      const int kb = (kk + 1) * 32 + s_c;
      a_reg = *(const bf16x8*)(Ap + arow * 384 + kb);
#pragma unroll
      for (int h = 0; h < 3; ++h)
        b_reg[h] = *(const bf16x8*)(W + (size_t)(col0 + s_row + 64 * h) * 384 + kb);
    }
    bf16x8 af[4];
#pragma unroll
    for (int mt = 0; mt < 4; ++mt) af[mt] = *(const bf16x8*)(&Al[mt * 16 + r][g * 8]);
#pragma unroll
    for (int nt = 0; nt < 3; ++nt) {
      bf16x8 bf = *(const bf16x8*)(&Bl[n0 + nt * 16 + r][g * 8]);
#pragma unroll
      for (int mt = 0; mt < 4; ++mt)
        acc[mt][nt] = __builtin_amdgcn_mfma_f32_16x16x32_bf16(af[mt], bf, acc[mt][nt], 0, 0, 0);
    }
    __syncthreads();
  }

#pragma unroll
  for (int mt = 0; mt < 4; ++mt) {
#pragma unroll
    for (int j = 0; j < 4; ++j) {
      const int row = row0 + mt * 16 + g * 4 + j;
#pragma unroll
      for (int nt = 0; nt < 3; ++nt) {
        const int col = col0 + n0 + nt * 16 + r;
        float v = acc[mt][nt][j] + bias[col];
        const int s = col / 384, cs = col - s * 384;
        if (s == 0) v *= SCALE_;
        outp[(size_t)s * RS + (size_t)row * 384 + cs] = __float2bfloat16(v);
      }
    }
  }
}

// ---------- gemm5 C2: final = bf16(x2b) + (y2 @ c2^T)*bn3g + bn3b ----------
__global__ __launch_bounds__(256) void gemm5_c2(const __hip_bfloat16* __restrict__ Ap,
                                                const __hip_bfloat16* __restrict__ W,
                                                const float* __restrict__ bias,
                                                const float* __restrict__ p0,
                                                const float* __restrict__ p1,
                                                const __hip_bfloat16* __restrict__ x2b,
                                                float* __restrict__ outp) {
  const int tid = threadIdx.x;
  const int lane = tid & 63, wave = tid >> 6;
  const int g = lane >> 4, r = lane & 15;
  const int row0 = blockIdx.x * 64;
  const int col0 = blockIdx.y * 192;
  const int n0 = wave * 48;

  __shared__ __align__(16) __hip_bfloat16 Al[64][40];
  __shared__ __align__(16) __hip_bfloat16 Bl[192][40];

  const int s_row = tid >> 2, s_c = (tid & 3) * 8;
  const size_t arow = (size_t)(row0 + s_row);

  f32x4 acc[4][3] = {};
  bf16x8 a_reg = *(const bf16x8*)(Ap + arow * 384 + s_c);
  bf16x8 b_reg[3];
#pragma unroll
  for (int h = 0; h < 3; ++h)
    b_reg[h] = *(const bf16x8*)(W + (size_t)(col0 + s_row + 64 * h) * 384 + s_c);

  for (int kk = 0; kk < 12; ++kk) {
    *(bf16x8*)(&Al[s_row][s_c]) = a_reg;
#pragma unroll
    for (int h = 0; h < 3; ++h) *(bf16x8*)(&Bl[s_row + 64 * h][s_c]) = b_reg[h];
    __syncthreads();
    if (kk + 1 < 12) {
      const int kb = (kk + 1) * 32 + s_c;
      a_reg = *(const bf16x8*)(Ap + arow * 384 + kb);
#pragma unroll
      for (int h = 0; h < 3; ++h)
        b_reg[h] = *(const bf16x8*)(W + (size_t)(col0 + s_row + 64 * h) * 384 + kb);
    }
    bf16x8 af[4];
#pragma unroll
    for (int mt = 0; mt < 4; ++mt) af[mt] = *(const bf16x8*)(&Al[mt * 16 + r][g * 8]);
#pragma unroll
    for (int nt = 0; nt < 3; ++nt) {
      bf16x8 bf = *(const bf16x8*)(&Bl[n0 + nt * 16 + r][g * 8]);
#pragma unroll
      for (int mt = 0; mt < 4; ++mt)
        acc[mt][nt] = __builtin_amdgcn_mfma_f32_16x16x32_bf16(af[mt], bf, acc[mt][nt], 0, 0, 0);
    }
    __syncthreads();
  }

#pragma unroll
  for (int mt = 0; mt < 4; ++mt) {
#pragma unroll
    for (int j = 0; j < 4; ++j) {
      const int row = row0 + mt * 16 + g * 4 + j;
#pragma unroll
      for (int nt = 0; nt < 3; ++nt) {
        const int col = col0 + n0 + nt * 16 + r;
        float v = acc[mt][nt][j] + bias[col];
        float y = v * p0[col] + p1[col];
        float x2v = __bfloat162float(x2b[(size_t)row * 384 + col]);
        outp[(size_t)row * 384 + col] = x2v + y;
      }
    }
  }
}

// ---------- se2: x2b = bf16(x1b*sigmoid(g1@W^T+b)) in-place over x1b; fp32 LN stats ----------
__global__ __launch_bounds__(256) void se2_kernel(const __hip_bfloat16* __restrict__ g1,
                                                  const __hip_bfloat16* __restrict__ W,
                                                  const float* __restrict__ bias,
                                                  __hip_bfloat16* __restrict__ x1b,  // in: x1b, out: x2b
                                                  float* __restrict__ stats) {
  constexpr int KD = 192;
  const int tid = threadIdx.x;
  const int lane = tid & 63, wave = tid >> 6;
  const int g = lane >> 4, r = lane & 15;
  const int row0 = blockIdx.x * 64;
  const int col0 = blockIdx.y * 192;
  const int n0 = wave * 48;

  __shared__ __align__(16) __hip_bfloat16 Al[64][40];
  __shared__ __align__(16) __hip_bfloat16 Bl[192][40];
  __shared__ float st[512];

  const int s_row = tid >> 2, s_c = (tid & 3) * 8;
  const size_t arow = (size_t)(row0 + s_row);

  f32x4 acc[4][3] = {};
  bf16x8 a_reg = *(const bf16x8*)(g1 + arow * KD + s_c);
  bf16x8 b_reg[3];
#pragma unroll
  for (int h = 0; h < 3; ++h)
    b_reg[h] = *(const bf16x8*)(W + (size_t)(col0 + s_row + 64 * h) * KD + s_c);

  for (int kk = 0; kk < 6; ++kk) {
    *(bf16x8*)(&Al[s_row][s_c]) = a_reg;
#pragma unroll
    for (int h = 0; h < 3; ++h) *(bf16x8*)(&Bl[s_row + 64 * h][s_c]) = b_reg[h];
    __syncthreads();
    if (kk + 1 < 6) {
      const int kb = (kk + 1) * 32 + s_c;
      a_reg = *(const bf16x8*)(g1 + arow * KD + kb);
#pragma unroll
      for (int h = 0; h < 3; ++h)
        b_reg[h] = *(const bf16x8*)(W + (size_t)(col0 + s_row + 64 * h) * KD + kb);
    }
    bf16x8 af[4];
#pragma unroll
    for (int mt = 0; mt < 4; ++mt) af[mt] = *(const bf16x8*)(&Al[mt * 16 + r][g * 8]);
#pragma unroll
    for (int nt = 0; nt < 3; ++nt) {
      bf16x8 bf = *(const bf16x8*)(&Bl[n0 + nt * 16 + r][g * 8]);
#pragma unroll
      for (int mt = 0; mt < 4; ++mt)
        acc[mt][nt] = __builtin_amdgcn_mfma_f32_16x16x32_bf16(af[mt], bf, acc[mt][nt], 0, 0, 0);
    }
    __syncthreads();
  }

#pragma unroll
  for (int mt = 0; mt < 4; ++mt) {
#pragma unroll
    for (int j = 0; j < 4; ++j) {
      const int lrow = mt * 16 + g * 4 + j;
      const size_t ob = (size_t)(row0 + lrow) * 384;
      float s = 0.f, sq = 0.f;
#pragma unroll
      for (int nt = 0; nt < 3; ++nt) {
        const int col = col0 + n0 + nt * 16 + r;
        float v = acc[mt][nt][j] + bias[col];
        float gate = 1.f / (1.f + __expf(-v));
        float x1v = __bfloat162float(x1b[ob + col]);
        float x2 = x1v * gate;
        x1b[ob + col] = __float2bfloat16(x2);   // in-place: same thread read->write
        s += x2; sq += x2 * x2;
      }
#pragma unroll
      for (int m = 1; m < 16; m <<= 1) { s += __shfl_xor(s, m, 64); sq += __shfl_xor(sq, m, 64); }
      if (r == 0) { st[wave * 128 + lrow] = s; st[wave * 128 + 64 + lrow] = sq; }
    }
  }
  __syncthreads();
  if (tid < 64) {
    float s = st[tid] + st[128 + tid] + st[256 + tid] + st[384 + tid];
    float sq = st[64 + tid] + st[192 + tid] + st[320 + tid] + st[448 + tid];
    stats[(size_t)(row0 + tid) * 4 + blockIdx.y * 2] = s;
    stats[(size_t)(row0 + tid) * 4 + blockIdx.y * 2 + 1] = sq;
  }
}

// ---------- c1ln: y1 = gelu(LN2(x2b) @ c1^T)*bn1+bn1b with LN folded (gc1/S1/bb) ----------
__global__ __launch_bounds__(256) void c1ln_kernel(const __hip_bfloat16* __restrict__ x2b,
                                                   const float* __restrict__ stats,
                                                   const __hip_bfloat16* __restrict__ gc1,
                                                   const float* __restrict__ S1,
                                                   const float* __restrict__ bb,
                                                   const float* __restrict__ bn1g_,
                                                   const float* __restrict__ bn1b_,
                                                   __hip_bfloat16* __restrict__ y1) {
  const int tid = threadIdx.x;
  const int lane = tid & 63, wave = tid >> 6;
  const int g = lane >> 4, r = lane & 15;
  const int row0 = blockIdx.x * 64;
  const int col0 = blockIdx.y * 192;
  const int n0 = wave * 48;

  __shared__ __align__(16) __hip_bfloat16 Al[64][40];
  __shared__ __align__(16) __hip_bfloat16 Bl[192][40];
  __shared__ float mean_l[64], rstd_l[64];

  const int s_row = tid >> 2, s_c = (tid & 3) * 8;
  const size_t abase = (size_t)(row0 + s_row) * 384;

  if (tid < 64) {
    const size_t row = row0 + tid;
    float s = stats[row * 4] + stats[row * 4 + 2];
    float sq = stats[row * 4 + 1] + stats[row * 4 + 3];
    float mean = s * (1.f / 384.f);
    float var = sq * (1.f / 384.f) - mean * mean;
    mean_l[tid] = mean;
    rstd_l[tid] = rsqrtf(var + 1e-5f);
  }

  f32x4 acc[4][3] = {};
  bf16x8 a_reg = *(const bf16x8*)(x2b + abase + s_c);
  bf16x8 b_reg[3];
#pragma unroll
  for (int h = 0; h < 3; ++h)
    b_reg[h] = *(const bf16x8*)(gc1 + (size_t)(col0 + s_row + 64 * h) * 384 + s_c);

  for (int kk = 0; kk < 12; ++kk) {
    *(bf16x8*)(&Al[s_row][s_c]) = a_reg;
#pragma unroll
    for (int h = 0; h < 3; ++h) *(bf16x8*)(&Bl[s_row + 64 * h][s_c]) = b_reg[h];
    __syncthreads();
    if (kk + 1 < 12) {
      const int kb = (kk + 1) * 32 + s_c;
      a_reg = *(const bf16x8*)(x2b + abase + kb);
#pragma unroll
      for (int h = 0; h < 3; ++h)
        b_reg[h] = *(const bf16x8*)(gc1 + (size_t)(col0 + s_row + 64 * h) * 384 + kb);
    }
    bf16x8 af[4];
#pragma unroll
    for (int mt = 0; mt < 4; ++mt) af[mt] = *(const bf16x8*)(&Al[mt * 16 + r][g * 8]);
#pragma unroll
    for (int nt = 0; nt < 3; ++nt) {
      bf16x8 bf = *(const bf16x8*)(&Bl[n0 + nt * 16 + r][g * 8]);
#pragma unroll
      for (int mt = 0; mt < 4; ++mt)
        acc[mt][nt] = __builtin_amdgcn_mfma_f32_16x16x32_bf16(af[mt], bf, acc[mt][nt], 0, 0, 0);
    }
    __syncthreads();
  }

#pragma unroll
  for (int mt = 0; mt < 4; ++mt) {
#pragma unroll
    for (int j = 0; j < 4; ++j) {
      const int rl = mt * 16 + g * 4 + j;
      const int row = row0 + rl;
      const float mean = mean_l[rl], rstd = rstd_l[rl];
#pragma unroll
      for (int nt = 0; nt < 3; ++nt) {
        const int col = col0 + n0 + nt * 16 + r;
        float v = rstd * (acc[mt][nt][j] - mean * S1[col]) + bb[col];
        float gl = 0.5f * v * (1.f + erff(v * 0.70710678118654752f));
        y1[(size_t)row * 384 + col] = __float2bfloat16(gl * bn1g_[col] + bn1b_[col]);
      }
    }
  }
}

// ---------- proj: x1 = x + proj(ao); x1 -> bf16 only; fused SE1 -> g1 ----------
__global__ __launch_bounds__(256) void proj_kernel(const __hip_bfloat16* __restrict__ aoc0,
                                                   const __hip_bfloat16* __restrict__ aoc1,
                                                   const __hip_bfloat16* __restrict__ W,
                                                   const float* __restrict__ bias,
                                                   const float* __restrict__ x,
                                                   __hip_bfloat16* __restrict__ x1b,
                                                   const __hip_bfloat16* __restrict__ W2,
                                                   const float* __restrict__ bias2,
                                                   __hip_bfloat16* __restrict__ g1) {
  constexpr int NT = 6;
  const int tid = threadIdx.x;
  const int lane = tid & 63, wave = tid >> 6;
  const int g = lane >> 4, r = lane & 15;
  const int row0 = blockIdx.x * 64;
  const int n0 = wave * 96;

  __shared__ __align__(16) char smem[50176];
  auto Al = (__hip_bfloat16(*)[40])smem;
  auto Bl = (__hip_bfloat16(*)[40])(smem + 64 * 80);

  const int s_row = tid >> 2;
  const int s_c = (tid & 3) * 8;

  const __hip_bfloat16* ap;
  {
    int t = row0 + s_row;
    int b = t / 3136, l = t - b * 3136;
    int i = l / 56, j = l - i * 56;
    int hp = i >= 3 ? i - 3 : i + 53;
    int wp = j >= 3 ? j - 3 : j + 53;
    size_t arow = ((size_t)(b * 64 + (hp / 7) * 8 + wp / 7)) * 49 + (hp % 7) * 7 + (wp % 7);
    ap = (arow < (size_t)HT) ? (aoc0 + arow * 384) : (aoc1 + (arow - HT) * 384);
  }

  f32x4 acc[4][NT] = {};

  bf16x8 a_reg = *(const bf16x8*)(ap + s_c);
  bf16x8 b_reg[NT];
#pragma unroll
  for (int h = 0; h < NT; ++h)
    b_reg[h] = *(const bf16x8*)(W + (size_t)(s_row + 64 * h) * 384 + s_c);

  for (int kk = 0; kk < 12; ++kk) {
    *(bf16x8*)(&Al[s_row][s_c]) = a_reg;
#pragma unroll
    for (int h = 0; h < NT; ++h) *(bf16x8*)(&Bl[s_row + 64 * h][s_c]) = b_reg[h];
    __syncthreads();
    if (kk + 1 < 12) {
      const int kb = (kk + 1) * 32 + s_c;
      a_reg = *(const bf16x8*)(ap + kb);
#pragma unroll
      for (int h = 0; h < NT; ++h)
        b_reg[h] = *(const bf16x8*)(W + (size_t)(s_row + 64 * h) * 384 + kb);
    }
    bf16x8 af[4];
#pragma unroll
    for (int mt = 0; mt < 4; ++mt) af[mt] = *(const bf16x8*)(&Al[mt * 16 + r][g * 8]);
#pragma unroll
    for (int nt = 0; nt < NT; ++nt) {
      bf16x8 bf = *(const bf16x8*)(&Bl[n0 + nt * 16 + r][g * 8]);
#pragma unroll
      for (int mt = 0; mt < 4; ++mt)
        acc[mt][nt] = __builtin_amdgcn_mfma_f32_16x16x32_bf16(af[mt], bf, acc[mt][nt], 0, 0, 0);
    }
    __syncthreads();
  }

  auto Xt = (__hip_bfloat16(*)[392])smem;
#pragma unroll
  for (int mt = 0; mt < 4; ++mt)
#pragma unroll
    for (int j = 0; j < 4; ++j) {
      const int lrow = mt * 16 + g * 4 + j;
      const size_t ob = (size_t)(row0 + lrow) * 384;
#pragma unroll
      for (int nt = 0; nt < NT; ++nt) {
        const int col = n0 + nt * 16 + r;
        float v = acc[mt][nt][j] + bias[col] + x[ob + col];
        __hip_bfloat16 hb = __float2bfloat16(v);
        x1b[ob + col] = hb;
        Xt[lrow][col] = hb;
      }
    }
  __syncthreads();
  f32x4 acc2[4][3] = {};
  const int c0 = wave * 48;
  for (int kk = 0; kk < 12; ++kk) {
    bf16x8 af2[4];
#pragma unroll
    for (int mt = 0; mt < 4; ++mt)
      af2[mt] = *(const bf16x8*)(&Xt[mt * 16 + r][kk * 32 + g * 8]);
#pragma unroll
    for (int nt2 = 0; nt2 < 3; ++nt2) {
      bf16x8 b2 = *(const bf16x8*)(W2 + (size_t)(c0 + nt2 * 16 + r) * 384 + kk * 32 + g * 8);
#pragma unroll
      for (int mt = 0; mt < 4; ++mt)
        acc2[mt][nt2] = __builtin_amdgcn_mfma_f32_16x16x32_bf16(af2[mt], b2, acc2[mt][nt2], 0, 0, 0);
    }
  }
#pragma unroll
  for (int mt = 0; mt < 4; ++mt)
#pragma unroll
    for (int j = 0; j < 4; ++j) {
      const size_t row = row0 + mt * 16 + g * 4 + j;
#pragma unroll
      for (int nt2 = 0; nt2 < 3; ++nt2) {
        const int col2 = c0 + nt2 * 16 + r;
        float v = acc2[mt][nt2][j] + bias2[col2];
        g1[row * 192 + col2] = __float2bfloat16(fmaxf(v, 0.f));
      }
    }
}

// ---------- attention core: one 64-thread block per (window, head); ao chunk-local ----------
__global__ __launch_bounds__(64) void attn_core(const __hip_bfloat16* __restrict__ qkv,
                                                const float* __restrict__ rpb,
                                                __hip_bfloat16* __restrict__ ao, int win0) {
  const int bid = blockIdx.x;
  const int win_l = bid / 12, head = bid - win_l * 12;
  const int widx = (win0 + win_l) & 63;
  const int lane = threadIdx.x;
  const int g = lane >> 4, r = lane & 15;
  const int wbh = (widx >> 3) * 7, wbw = (widx & 7) * 7;
  const size_t rowbase = (size_t)(win_l * 49) * 384 + head * 32;
  const __hip_bfloat16* q_g = qkv + rowbase;
  const __hip_bfloat16* k_g = qkv + RS + rowbase;
  const __hip_bfloat16* v_g = qkv + 2 * RS + rowbase;

  __shared__ __align__(16) __hip_bfloat16 P_l[49 * 64];
  __shared__ __align__(16) unsigned short vT[32 * 72];

  bf16x8 zf;
#pragma unroll
  for (int i = 0; i < 8; ++i) zf[i] = tobf(0.f);

  for (int i = lane; i < 512; i += 64) {
    int d = i >> 4, t = 48 + (i & 15);
    vT[d * 72 + t] = 0;
  }
  if (lane < 49) {
#pragma unroll
    for (int c = 0; c < 4; ++c) {
      u16x8 vv = *(const u16x8*)(v_g + (size_t)lane * 384 + c * 8);
#pragma unroll
      for (int e = 0; e < 8; ++e) vT[(c * 8 + e) * 72 + lane] = vv[e];
    }
  }

  int yj4[4], xj4[4], rj4[4];
  bool val4[4];
#pragma unroll
  for (int nt = 0; nt < 4; ++nt) {
    int jt = nt * 16 + r;
    val4[nt] = jt < 49;
    int jc = val4[nt] ? jt : 0;
    int yj = jc / 7, xj = jc - yj * 7;
    yj4[nt] = yj; xj4[nt] = xj;
    int hj = wbh + yj, wj = wbw + xj;
    rj4[nt] = (hj < 49 ? 0 : (hj < 53 ? 1 : 2)) * 3 + (wj < 49 ? 0 : (wj < 53 ? 1 : 2));
  }

  f32x4 sA[4][4] = {};
  {
    bf16x8 qa[4];
#pragma unroll
    for (int mt = 0; mt < 4; ++mt) {
      int row = mt * 16 + r;
      qa[mt] = (row < 49) ? *(const bf16x8*)(q_g + (size_t)row * 384 + g * 8) : zf;
    }
#pragma unroll
    for (int nt = 0; nt < 4; ++nt) {
      int rowk = nt * 16 + r;
      bf16x8 kf = (rowk < 49) ? *(const bf16x8*)(k_g + (size_t)rowk * 384 + g * 8) : zf;
#pragma unroll
      for (int mt = 0; mt < 4; ++mt)
        sA[mt][nt] = __builtin_amdgcn_mfma_f32_16x16x32_bf16(qa[mt], kf, sA[mt][nt], 0, 0, 0);
    }
  }
#pragma unroll
  for (int mt = 0; mt < 4; ++mt) {
#pragma unroll
    for (int j = 0; j < 4; ++j) {
      const int it = mt * 16 + g * 4 + j;
      if (it < 49) {
        int yi = it / 7, xi = it - yi * 7;
        int hi = wbh + yi, wi2 = wbw + xi;
        int ri = (hi < 49 ? 0 : (hi < 53 ? 1 : 2)) * 3 + (wi2 < 49 ? 0 : (wi2 < 53 ? 1 : 2));
        float v4[4];
#pragma unroll
        for (int nt = 0; nt < 4; ++nt) {
          float sv = -1e30f;
          if (val4[nt]) {
            sv = sA[mt][nt][j] + rpb[((yi - yj4[nt] + 6) * 13 + (xi - xj4[nt] + 6)) * 12 + head];
            if (ri != rj4[nt]) sv -= 100.f;
          }
          v4[nt] = sv;
        }
        float mx = fmaxf(fmaxf(v4[0], v4[1]), fmaxf(v4[2], v4[3]));
#pragma unroll
        for (int m = 1; m < 16; m <<= 1) mx = fmaxf(mx, __shfl_xor(mx, m, 64));
        float sum = 0.f;
#pragma unroll
        for (int nt = 0; nt < 4; ++nt) { v4[nt] = __expf(v4[nt] - mx); sum += v4[nt]; }
#pragma unroll
        for (int m = 1; m < 16; m <<= 1) sum += __shfl_xor(sum, m, 64);
        float inv = 1.f / sum;
#pragma unroll
        for (int nt = 0; nt < 4; ++nt) {
          int col = nt * 16 + r;
          int swz = ((col >> 3) ^ (it & 7));
          P_l[it * 64 + swz * 8 + (col & 7)] = __float2bfloat16(v4[nt] * inv);
        }
      }
    }
  }
  f32x4 oA[4][2] = {};
#pragma unroll
  for (int ks = 0; ks < 2; ++ks) {
    bf16x8 pa[4];
#pragma unroll
    for (int mt = 0; mt < 4; ++mt) {
      int row = mt * 16 + r;
      int swz = (ks * 4 + g) ^ (row & 7);
      pa[mt] = (row < 49) ? *(const bf16x8*)(&P_l[row * 64 + swz * 8]) : zf;
    }
#pragma unroll
    for (int nt = 0; nt < 2; ++nt) {
      bf16x8 vbv = *(const bf16x8*)(&vT[(nt * 16 + r) * 72 + ks * 32 + g * 8]);
#pragma unroll
      for (int mt = 0; mt < 4; ++mt)
        oA[mt][nt] = __builtin_amdgcn_mfma_f32_16x16x32_bf16(pa[mt], vbv, oA[mt][nt], 0, 0, 0);
    }
  }
#pragma unroll
  for (int mt = 0; mt < 4; ++mt)
#pragma unroll
    for (int nt = 0; nt < 2; ++nt)
#pragma unroll
      for (int j = 0; j < 4; ++j) {
        int row = mt * 16 + g * 4 + j;
        if (row < 49)
          ao[((size_t)win_l * 49 + row) * 384 + head * 32 + nt * 16 + r] =
              __float2bfloat16(oA[mt][nt][j]);
      }
}

// ---------- depthwise 3x3 (NHWC) + gelu*bn2 ----------
__global__ __launch_bounds__(256) void dw_kernel(const __hip_bfloat16* __restrict__ y1,
                                                 const float* __restrict__ wt,
                                                 const float* __restrict__ wb,
                                                 const float* __restrict__ g2,
                                                 const float* __restrict__ b2,
                                                 __hip_bfloat16* __restrict__ y2) {
  const int tid = blockIdx.x * 256 + threadIdx.x;
  const int c8 = tid % 48;
  int t = tid / 48;
  const int q = t & 3; t >>= 2;
  const int hq = t % 56;
  const int b = t / 56;
  const int cb = c8 * 8;
  const int x0 = q * 14;

  float wr[9][8];
#pragma unroll
  for (int k = 0; k < 9; ++k) {
    float4 a = *(const float4*)(wt + k * 384 + cb);
    float4 c = *(const float4*)(wt + k * 384 + cb + 4);
    wr[k][0] = a.x; wr[k][1] = a.y; wr[k][2] = a.z; wr[k][3] = a.w;
    wr[k][4] = c.x; wr[k][5] = c.y; wr[k][6] = c.z; wr[k][7] = c.w;
  }
  if (hq == 0) {
#pragma unroll
    for (int k = 0; k < 3; ++k)
#pragma unroll
      for (int i = 0; i < 8; ++i) wr[k][i] = 0.f;
  }
  if (hq == 55) {
#pragma unroll
    for (int k = 6; k < 9; ++k)
#pragma unroll
      for (int i = 0; i < 8; ++i) wr[k][i] = 0.f;
  }
  float bias[8], gv[8], bv[8];
  {
    float4 a = *(const float4*)(wb + cb), c = *(const float4*)(wb + cb + 4);
    bias[0] = a.x; bias[1] = a.y; bias[2] = a.z; bias[3] = a.w;
    bias[4] = c.x; bias[5] = c.y; bias[6] = c.z; bias[7] = c.w;
    float4 d = *(const float4*)(g2 + cb), e = *(const float4*)(g2 + cb + 4);
    gv[0] = d.x; gv[1] = d.y; gv[2] = d.z; gv[3] = d.w;
    gv[4] = e.x; gv[5] = e.y; gv[6] = e.z; gv[7] = e.w;
    float4 f = *(const float4*)(b2 + cb), h = *(const float4*)(b2 + cb + 4);
    bv[0] = f.x; bv[1] = f.y; bv[2] = f.z; bv[3] = f.w;
    bv[4] = h.x; bv[5] = h.y; bv[6] = h.z; bv[7] = h.w;
  }
  const int hm = hq > 0 ? hq - 1 : 0;
  const int hp = hq < 55 ? hq + 1 : 55;
  const __hip_bfloat16* r0 = y1 + ((size_t)(b * 3136 + hm * 56)) * 384 + cb;
  const __hip_bfloat16* r1 = y1 + ((size_t)(b * 3136 + hq * 56)) * 384 + cb;
  const __hip_bfloat16* r2 = y1 + ((size_t)(b * 3136 + hp * 56)) * 384 + cb;
  __hip_bfloat16* op = y2 + ((size_t)(b * 3136 + hq * 56)) * 384 + cb;

  u16x8 zv;
#pragma unroll
  for (int i = 0; i < 8; ++i) zv[i] = 0;
#define LDC(rp, x) (((unsigned)(x) < 56u) ? *(const u16x8*)((rp) + (size_t)(x) * 384) : zv)

  u16x8 L0 = LDC(r0, x0 - 1), L1 = LDC(r1, x0 - 1), L2 = LDC(r2, x0 - 1);
  u16x8 C0 = LDC(r0, x0), C1 = LDC(r1, x0), C2 = LDC(r2, x0);
#pragma unroll
  for (int xi = 0; xi < 14; ++xi) {
    const int x = x0 + xi;
    u16x8 R0 = LDC(r0, x + 1), R1 = LDC(r1, x + 1), R2 = LDC(r2, x + 1);
    float acc[8];
#pragma unroll
    for (int i = 0; i < 8; ++i) acc[i] = bias[i];
#pragma unroll
    for (int i = 0; i < 8; ++i) {
      acc[i] += __uint_as_float((unsigned)L0[i] << 16) * wr[0][i];
      acc[i] += __uint_as_float((unsigned)C0[i] << 16) * wr[1][i];
      acc[i] += __uint_as_float((unsigned)R0[i] << 16) * wr[2][i];
      acc[i] += __uint_as_float((unsigned)L1[i] << 16) * wr[3][i];
      acc[i] += __uint_as_float((unsigned)C1[i] << 16) * wr[4][i];
      acc[i] += __uint_as_float((unsigned)R1[i] << 16) * wr[5][i];
      acc[i] += __uint_as_float((unsigned)L2[i] << 16) * wr[6][i];
      acc[i] += __uint_as_float((unsigned)C2[i] << 16) * wr[7][i];
      acc[i] += __uint_as_float((unsigned)R2[i] << 16) * wr[8][i];
    }
    u16x8 o;
#pragma unroll
    for (int i = 0; i < 8; ++i) {
      float u = acc[i];
      float gl = 0.5f * u * (1.f + erff(u * 0.70710678118654752f));
      o[i] = f2u(gl * gv[i] + bv[i]);
    }
    *(u16x8*)(op + (size_t)x * 384) = o;
    L0 = C0; L1 = C1; L2 = C2;
    C0 = R0; C1 = R1; C2 = R2;
  }
#undef LDC
}

extern "C" void kernel_launch(void* const* d_in, const int* in_sizes, int n_in, void* d_out,
                              int out_size, void* d_ws, size_t ws_size, hipStream_t stream) {
  (void)in_sizes; (void)n_in; (void)out_size; (void)ws_size;
  const float* x = (const float*)d_in[0];
  const float* n1g = (const float*)d_in[1];
  const float* n1b = (const float*)d_in[2];
  const float* qkv_w = (const float*)d_in[3];
  const float* qkv_b = (const float*)d_in[4];
  const float* rpb = (const float*)d_in[5];
  const float* proj_w = (const float*)d_in[6];
  const float* proj_b = (const float*)d_in[7];
  const float* se1_w = (const float*)d_in[8];
  const float* se1_b = (const float*)d_in[9];
  const float* se2_w = (const float*)d_in[10];
  const float* se2_b = (const float*)d_in[11];
  const float* n2g = (const float*)d_in[12];
  const float* n2b = (const float*)d_in[13];
  const float* c1_w = (const float*)d_in[14];
  const float* c1_b = (const float*)d_in[15];
  const float* bn1g = (const float*)d_in[16];
  const float* bn1b = (const float*)d_in[17];
  const float* dw_w = (const float*)d_in[18];
  const float* dw_b = (const float*)d_in[19];
  const float* bn2g = (const float*)d_in[20];
  const float* bn2b = (const float*)d_in[21];
  const float* c2_w = (const float*)d_in[22];
  const float* c2_b = (const float*)d_in[23];
  const float* bn3g = (const float*)d_in[24];
  const float* bn3b = (const float*)d_in[25];

  char* ws = (char*)d_ws;
  __hip_bfloat16* r0b = (__hip_bfloat16*)ws;              // R0: xn -> aoc1/stats/g1 -> y2
  __hip_bfloat16* r1b = (__hip_bfloat16*)(ws + OFF_R1);   // R1: x1b -> x2b (in place)
  __hip_bfloat16* wbp = (__hip_bfloat16*)(ws + OFF_WB);
  float* wt = (float*)(ws + OFF_WT);
  float* S1 = (float*)(ws + OFF_SB);
  float* bb = S1 + 384;
  __hip_bfloat16* qkv_wb = wbp;             // 442368
  __hip_bfloat16* proj_wb = wbp + 442368;   // 147456
  __hip_bfloat16* se1_wb = wbp + 589824;    // 73728
  __hip_bfloat16* se2_wb = wbp + 663552;    // 73728
  __hip_bfloat16* gc1 = wbp + 737280;       // 147456 (c1_w * n2g, bf16)
  __hip_bfloat16* c2_wb = wbp + 884736;     // 147456
  float* out = (float*)d_out;

  // chunked ao locations
  __hip_bfloat16* aoc0 = (__hip_bfloat16*)d_out + 3 * RS;  // d_out tail (after qkv scratch)
  __hip_bfloat16* aoc1 = r0b;                              // R0[0:38.5MB]
  __hip_bfloat16* g1 = r0b + (size_t)HT * 384;             // R0[38.5:77MB]
  float* stats = (float*)r0b;                              // R0[0:1.6MB] (after proj done)
  __hip_bfloat16* y1 = (__hip_bfloat16*)d_out;             // d_out[0:77MB] (qkv scratch dead)

  cvt_kernel<<<1728, 256, 0, stream>>>(qkv_w, qkv_wb, 442368);
  cvt_kernel<<<576, 256, 0, stream>>>(proj_w, proj_wb, 147456);
  cvt_kernel<<<288, 256, 0, stream>>>(se1_w, se1_wb, 73728);
  cvt_kernel<<<288, 256, 0, stream>>>(se2_w, se2_wb, 73728);
  cvt_kernel<<<576, 256, 0, stream>>>(c2_w, c2_wb, 147456);
  c1prep_kernel<<<96, 256, 0, stream>>>(c1_w, c1_b, n2g, n2b, gc1, S1, bb);
  dwrep_kernel<<<14, 256, 0, stream>>>(dw_w, wt);

  // LN1 + shift + window partition -> xn (R0, bf16, windowed)
  ln_kernel<true><<<25088, 256, 0, stream>>>(x, n1g, n1b, r0b);

  // attention: 2 chunks; qkv -> d_out[0:115.6MB]; ao: chunk0 -> d_out tail, chunk1 -> R0[0:38.5]
  for (int c = 0; c < 2; ++c) {
    const __hip_bfloat16* xa = r0b + (size_t)c * HT * 384;
    qkv_gemm5<<<dim3(784, 6), 256, 0, stream>>>(xa, qkv_wb, qkv_b, (__hip_bfloat16*)out);
    attn_core<<<12288, 64, 0, stream>>>((const __hip_bfloat16*)out, rpb,
                                        c == 0 ? aoc0 : aoc1, c * 1024);
  }

  // proj + residual -> x1b bf16 (R1) ; fused SE1 -> g1 (R0[38.5:77])
  proj_kernel<<<1568, 256, 0, stream>>>(aoc0, aoc1, proj_wb, proj_b, x, r1b, se1_wb, se1_b, g1);
  // x2b = bf16(x1b*sigmoid(g1@se2^T)) in-place over R1 ; fp32 LN stats -> R0[0:1.6MB]
  se2_kernel<<<dim3(1568, 2), 256, 0, stream>>>(g1, se2_wb, se2_b, r1b, stats);
  // y1 = gelu(LN2(x2b) @ c1^T)*bn1 -> d_out[0:77MB] bf16 (qkv scratch dead)
  c1ln_kernel<<<dim3(1568, 2), 256, 0, stream>>>(r1b, stats, gc1, S1, bb, bn1g, bn1b, y1);
  // y2 = gelu(dwconv(y1))*bn2 -> R0 (g1/stats dead)
  dw_kernel<<<1344, 256, 0, stream>>>(y1, wt, dw_b, bn2g, bn2b, r0b);
  // out = x2b + (y2 @ c2^T)*bn3 -> d_out fp32 (y1 dead)
  gemm5_c2<<<dim3(1568, 2), 256, 0, stream>>>(r0b, c2_wb, c2_b, bn3g, bn3b, r1b, out);
}